// Round 9
// baseline (907.125 us; speedup 1.0000x reference)
//
#include <hip/hip_runtime.h>
#include <math.h>

#define NN 50000
#define NE 800000
#define H 128

typedef short bf16x8 __attribute__((ext_vector_type(8)));
typedef unsigned short u16x8 __attribute__((ext_vector_type(8)));
typedef float f32x4 __attribute__((ext_vector_type(4)));
typedef unsigned short u16;

__device__ inline u16 f2b(float f) {
  unsigned u = __float_as_uint(f);
  return (u16)((u + 0x7FFF + ((u >> 16) & 1)) >> 16);
}
__device__ inline float b2f(u16 s) { return __uint_as_float(((unsigned)s) << 16); }

// =============== weight prep: bf16, transposed WT[n][k] = W[k][n] ===============
// WP element offsets:
//   ne2:0 gcn:16384(x3) skip:65536(x2)
//   t4:98304 (hn1,cn1,hn2,cn2 each 16384)
//   ab:163840 ee2:180224 cl2:196608(8192) ee1:204800([128][32]) eae:208896([128][32]) end:212992
__global__ void k_prep(const float* __restrict__ ea_w1, const float* __restrict__ cl_w1,
                       const float* __restrict__ ee_w2, const float* __restrict__ cl_w2,
                       const float* __restrict__ gcn_w, const float* __restrict__ skip_w,
                       const float* __restrict__ ne_w2, const float* __restrict__ ee_w1,
                       u16* __restrict__ WP) {
  int idx = blockIdx.x * 256 + threadIdx.x;
  if (idx >= 212992) return;
  float v;
  if (idx < 16384) {            // ne2
    int n = idx >> 7, k = idx & 127;
    v = ne_w2[k * 128 + n];
  } else if (idx < 65536) {     // gcn
    int lo = idx - 16384; int i = lo >> 14; int n = (lo >> 7) & 127, k = lo & 127;
    v = gcn_w[i * 16384 + k * 128 + n];
  } else if (idx < 98304) {     // skip
    int lo = idx - 65536; int i = lo >> 14; int n = (lo >> 7) & 127, k = lo & 127;
    v = skip_w[i * 16384 + k * 128 + n];
  } else if (idx < 163840) {    // t4: hn1, cn1, hn2, cn2
    int lo = idx - 98304; int tab = lo >> 14; int n = (lo >> 7) & 127, k = lo & 127;
    if (tab == 0) v = ea_w1[k * 128 + n];
    else if (tab == 1) v = cl_w1[k * 128 + n];
    else if (tab == 2) v = ea_w1[(128 + k) * 128 + n];
    else v = cl_w1[(128 + k) * 128 + n];
  } else if (idx < 180224) {    // ab
    int lo = idx - 163840; int n = lo >> 7, k = lo & 127;
    v = cl_w1[k * 128 + n] + cl_w1[(128 + k) * 128 + n];
  } else if (idx < 196608) {    // ee2
    int lo = idx - 180224; int n = lo >> 7, k = lo & 127;
    v = ee_w2[k * 128 + n];
  } else if (idx < 204800) {    // cl2 [64][128]
    int lo = idx - 196608; int n = lo >> 7, k = lo & 127;
    v = cl_w2[k * 64 + n];
  } else if (idx < 208896) {    // ee1 [128][32] zero-padded K
    int lo = idx - 204800; int n = lo >> 5, k = lo & 31;
    v = (k < 10) ? ee_w1[k * 128 + n] : 0.f;
  } else {                      // eae [128][32] zero-padded K (ea_w1 rows 256..265)
    int lo = idx - 208896; int n = lo >> 5, k = lo & 31;
    v = (k < 10) ? ea_w1[(256 + k) * 128 + n] : 0.f;
  }
  WP[idx] = f2b(v);
}

// =============== node encoder L1 ===============
__global__ __launch_bounds__(256) void k_rowenc(
    const float* __restrict__ x, const float* __restrict__ w1,
    const float* __restrict__ b1, u16* __restrict__ t1) {
  __shared__ float xs[16][10];
  int t = threadIdx.x;
  int base = blockIdx.x * 16;
  for (int idx = t; idx < 160; idx += 256) xs[idx / 10][idx % 10] = x[base * 10 + idx];
  __syncthreads();
  int j = t & 127, eg = t >> 7;
  float acc[8];
#pragma unroll
  for (int i = 0; i < 8; ++i) acc[i] = b1[j];
  for (int k = 0; k < 10; ++k) {
    float w = w1[k * H + j];
#pragma unroll
    for (int i = 0; i < 8; ++i) acc[i] += xs[eg * 8 + i][k] * w;
  }
#pragma unroll
  for (int i = 0; i < 8; ++i) t1[(long)(base + eg * 8 + i) * H + j] = f2b(fmaxf(acc[i], 0.f));
}

// =============== node-side GEMMs: BM=128 tiles ===============
// r8 tail analysis: 196-block dispatches fill only 196 of 512 resident-block slots
// (>half the machine idle per node GEMM). BM=128 -> 391 blocks/slice, 32 KB LDS,
// acc[2][8] (~132 total regs -> 3 waves/SIMD naturally; NO forced min-waves floor).

// ne2 GEMM: hb0 = hb1 @ ne_w2 + b2 (bf16 out)
__global__ __launch_bounds__(256, 2) void k_ngemm(
    const u16* __restrict__ A, const u16* __restrict__ WT,
    const float* __restrict__ bias, u16* __restrict__ outB) {
  __shared__ u16 As[128 * 128];
  int t = threadIdx.x;
  long base = (long)blockIdx.x * 128;
  for (int idx = t; idx < 128 * 16; idx += 256) {
    int row = idx >> 4, k8 = (idx & 15) * 8;
    long gr = base + row; if (gr >= NN) gr = 0;
    uint4 v = *(const uint4*)(A + gr * 128 + k8);
    *(uint4*)(As + row * 128 + (k8 ^ ((row & 7) * 8))) = v;
  }
  __syncthreads();
  int l = t & 63, w = t >> 6;
  int wrow = w * 32;
  int cl_ = l & 15, gr = l >> 4, ko = gr * 8;
  f32x4 acc[2][8];
#pragma unroll
  for (int nt = 0; nt < 8; ++nt) {
    float bb = bias[nt * 16 + cl_];
#pragma unroll
    for (int mt = 0; mt < 2; ++mt) { acc[mt][nt][0] = bb; acc[mt][nt][1] = bb; acc[mt][nt][2] = bb; acc[mt][nt][3] = bb; }
  }
#pragma unroll
  for (int c = 0; c < 4; ++c) {
    bf16x8 a[2], b[8];
#pragma unroll
    for (int mt = 0; mt < 2; ++mt) {
      int row = wrow + mt * 16 + cl_;
      a[mt] = *(const bf16x8*)(As + row * 128 + ((c * 32 + ko) ^ ((row & 7) * 8)));
    }
#pragma unroll
    for (int nt = 0; nt < 8; ++nt)
      b[nt] = *(const bf16x8*)(WT + (nt * 16 + cl_) * 128 + c * 32 + ko);
#pragma unroll
    for (int mt = 0; mt < 2; ++mt)
#pragma unroll
      for (int nt = 0; nt < 8; ++nt)
        acc[mt][nt] = __builtin_amdgcn_mfma_f32_16x16x32_bf16(a[mt], b[nt], acc[mt][nt], 0, 0, 0);
  }
#pragma unroll
  for (int mt = 0; mt < 2; ++mt)
#pragma unroll
    for (int r = 0; r < 4; ++r) {
      long row = base + wrow + mt * 16 + gr * 4 + r;
      if (row >= NN) continue;
#pragma unroll
      for (int nt = 0; nt < 8; ++nt)
        outB[row * 128 + nt * 16 + cl_] = f2b(acc[mt][nt][r]);
    }
}

// gcn(+skip) GEMM: y=0 -> mn = dinv*(h@gcn_w) bf16; y=1 -> A = h@skip_w f32
__global__ __launch_bounds__(256, 2) void k_gcnskip(
    const u16* __restrict__ Ain, const u16* __restrict__ WTg, const u16* __restrict__ WTs,
    const float* __restrict__ dinv, u16* __restrict__ mn, float* __restrict__ Af) {
  __shared__ u16 As[128 * 128];
  int t = threadIdx.x;
  long base = (long)blockIdx.x * 128;
  for (int idx = t; idx < 128 * 16; idx += 256) {
    int row = idx >> 4, k8 = (idx & 15) * 8;
    long gr = base + row; if (gr >= NN) gr = 0;
    uint4 v = *(const uint4*)(Ain + gr * 128 + k8);
    *(uint4*)(As + row * 128 + (k8 ^ ((row & 7) * 8))) = v;
  }
  __syncthreads();
  const u16* WT = blockIdx.y ? WTs : WTg;
  int l = t & 63, w = t >> 6;
  int wrow = w * 32;
  int cl_ = l & 15, gr = l >> 4, ko = gr * 8;
  f32x4 acc[2][8];
#pragma unroll
  for (int nt = 0; nt < 8; ++nt)
#pragma unroll
    for (int mt = 0; mt < 2; ++mt) { acc[mt][nt][0] = 0.f; acc[mt][nt][1] = 0.f; acc[mt][nt][2] = 0.f; acc[mt][nt][3] = 0.f; }
#pragma unroll
  for (int c = 0; c < 4; ++c) {
    bf16x8 a[2], b[8];
#pragma unroll
    for (int mt = 0; mt < 2; ++mt) {
      int row = wrow + mt * 16 + cl_;
      a[mt] = *(const bf16x8*)(As + row * 128 + ((c * 32 + ko) ^ ((row & 7) * 8)));
    }
#pragma unroll
    for (int nt = 0; nt < 8; ++nt)
      b[nt] = *(const bf16x8*)(WT + (nt * 16 + cl_) * 128 + c * 32 + ko);
#pragma unroll
    for (int mt = 0; mt < 2; ++mt)
#pragma unroll
      for (int nt = 0; nt < 8; ++nt)
        acc[mt][nt] = __builtin_amdgcn_mfma_f32_16x16x32_bf16(a[mt], b[nt], acc[mt][nt], 0, 0, 0);
  }
  bool isG = (blockIdx.y == 0);
#pragma unroll
  for (int mt = 0; mt < 2; ++mt)
#pragma unroll
    for (int r = 0; r < 4; ++r) {
      long row = base + wrow + mt * 16 + gr * 4 + r;
      if (row >= NN) continue;
      float dv = isG ? dinv[row] : 0.f;
#pragma unroll
      for (int nt = 0; nt < 8; ++nt) {
        int col = nt * 16 + cl_;
        if (isG) mn[row * 128 + col] = f2b(dv * acc[mt][nt][r]);
        else Af[row * 128 + col] = acc[mt][nt][r];
      }
    }
}

// 4-table GEMM: y in 0..3 -> T1/T2 halves
__global__ __launch_bounds__(256, 2) void k_ntab(
    const u16* __restrict__ A, const u16* __restrict__ WPt4,
    const float* __restrict__ ea_b1, const float* __restrict__ cl_b1,
    u16* __restrict__ T1, u16* __restrict__ T2) {
  __shared__ u16 As[128 * 128];
  int t = threadIdx.x;
  long base = (long)blockIdx.x * 128;
  for (int idx = t; idx < 128 * 16; idx += 256) {
    int row = idx >> 4, k8 = (idx & 15) * 8;
    long gr = base + row; if (gr >= NN) gr = 0;
    uint4 v = *(const uint4*)(A + gr * 128 + k8);
    *(uint4*)(As + row * 128 + (k8 ^ ((row & 7) * 8))) = v;
  }
  __syncthreads();
  int y = blockIdx.y;
  const u16* WT = WPt4 + y * 16384;
  const float* bias = (y == 0) ? ea_b1 : ((y == 1) ? cl_b1 : nullptr);
  u16* outT = (y < 2) ? T1 : T2;
  int colOff = (y & 1) * 128;
  int l = t & 63, w = t >> 6;
  int wrow = w * 32;
  int cl_ = l & 15, gr = l >> 4, ko = gr * 8;
  f32x4 acc[2][8];
#pragma unroll
  for (int nt = 0; nt < 8; ++nt) {
    float bb = bias ? bias[nt * 16 + cl_] : 0.f;
#pragma unroll
    for (int mt = 0; mt < 2; ++mt) { acc[mt][nt][0] = bb; acc[mt][nt][1] = bb; acc[mt][nt][2] = bb; acc[mt][nt][3] = bb; }
  }
#pragma unroll
  for (int c = 0; c < 4; ++c) {
    bf16x8 a[2], b[8];
#pragma unroll
    for (int mt = 0; mt < 2; ++mt) {
      int row = wrow + mt * 16 + cl_;
      a[mt] = *(const bf16x8*)(As + row * 128 + ((c * 32 + ko) ^ ((row & 7) * 8)));
    }
#pragma unroll
    for (int nt = 0; nt < 8; ++nt)
      b[nt] = *(const bf16x8*)(WT + (nt * 16 + cl_) * 128 + c * 32 + ko);
#pragma unroll
    for (int mt = 0; mt < 2; ++mt)
#pragma unroll
      for (int nt = 0; nt < 8; ++nt)
        acc[mt][nt] = __builtin_amdgcn_mfma_f32_16x16x32_bf16(a[mt], b[nt], acc[mt][nt], 0, 0, 0);
  }
#pragma unroll
  for (int mt = 0; mt < 2; ++mt)
#pragma unroll
    for (int r = 0; r < 4; ++r) {
      long row = base + wrow + mt * 16 + gr * 4 + r;
      if (row >= NN) continue;
#pragma unroll
      for (int nt = 0; nt < 8; ++nt)
        outT[row * 256 + colOff + nt * 16 + cl_] = f2b(acc[mt][nt][r]);
    }
}

// =============== degree ===============
__global__ void k_deg(const int* __restrict__ col, unsigned* __restrict__ deg) {
  int e = blockIdx.x * 256 + threadIdx.x;
  if (e < NE) atomicAdd(&deg[col[e]], 1u);
}

// =============== CSR build ===============
__global__ __launch_bounds__(256) void k_scan1(const unsigned* __restrict__ deg,
                                               int* __restrict__ bsum) {
  __shared__ int s[256];
  int t = threadIdx.x, v = blockIdx.x * 256 + t;
  s[t] = (v < NN) ? (int)deg[v] : 0;
  __syncthreads();
  for (int off = 128; off > 0; off >>= 1) {
    if (t < off) s[t] += s[t + off];
    __syncthreads();
  }
  if (t == 0) bsum[blockIdx.x] = s[0];
}
__global__ __launch_bounds__(256) void k_scan2(const int* __restrict__ bsum,
                                               int* __restrict__ boff, int nb) {
  __shared__ int s[256];
  int t = threadIdx.x;
  int v = (t < nb) ? bsum[t] : 0;
  s[t] = v;
  __syncthreads();
  for (int off = 1; off < 256; off <<= 1) {
    int x = (t >= off) ? s[t - off] : 0;
    __syncthreads();
    s[t] += x;
    __syncthreads();
  }
  if (t < nb) boff[t] = s[t] - v;
}
// scan3 also emits dinv (reads deg anyway; k_dinv launch removed)
__global__ __launch_bounds__(256) void k_scan3(const unsigned* __restrict__ deg,
                                               const int* __restrict__ boff,
                                               int* __restrict__ offs, int* __restrict__ cursor,
                                               float* __restrict__ dinv) {
  __shared__ int s[256];
  int t = threadIdx.x, v = blockIdx.x * 256 + t;
  int d = (v < NN) ? (int)deg[v] : 0;
  s[t] = d;
  __syncthreads();
  for (int off = 1; off < 256; off <<= 1) {
    int x = (t >= off) ? s[t - off] : 0;
    __syncthreads();
    s[t] += x;
    __syncthreads();
  }
  int excl = s[t] - d + boff[blockIdx.x];
  if (v < NN) {
    offs[v] = excl; cursor[v] = excl;
    dinv[v] = 1.0f / sqrtf((float)(d + 1));
  }
}
// k_fill records dest node (ecn) and original edge id (eid) per CSR slot so k_edge
// can process edges in CSR (cn-sorted) order for T2-gather locality (r8: -33% FETCH).
__global__ void k_fill(const int* __restrict__ ei, int* __restrict__ cursor,
                       int* __restrict__ elr, int* __restrict__ ecn, int* __restrict__ eid) {
  int e = blockIdx.x * 256 + threadIdx.x;
  if (e < NE) {
    int c = ei[NE + e];
    int pos = atomicAdd(&cursor[c], 1);
    elr[pos] = ei[e];
    ecn[pos] = c;
    eid[pos] = e;
  }
}

// =============== CSR aggregate + fused BN stats ===============
__global__ __launch_bounds__(256) void k_agg(
    const int* __restrict__ offs, const unsigned* __restrict__ deg,
    const int* __restrict__ elr, const float* __restrict__ dinv,
    const u16* __restrict__ mn, const float* __restrict__ gb,
    float* __restrict__ agg, double* __restrict__ sums) {
  __shared__ float s_lds[16][128];
  __shared__ float q_lds[16][128];
  int t = threadIdx.x;
  int slot = t >> 4;
  int j8 = (t & 15) * 8;
  float ps[8], pq[8];
#pragma unroll
  for (int k = 0; k < 8; ++k) { ps[k] = 0.f; pq[k] = 0.f; }
  int vbase = blockIdx.x * 64;
  for (int nn = 0; nn < 4; ++nn) {
    int v = vbase + nn * 16 + slot;
    if (v < NN) {
      float acc[8];
      u16x8 m0 = *(const u16x8*)(mn + (long)v * 128 + j8);
#pragma unroll
      for (int k = 0; k < 8; ++k) acc[k] = b2f(m0[k]);
      int start = offs[v];
      int cnt = (int)deg[v];
      for (int i = 0; i < cnt; ++i) {
        u16x8 m = *(const u16x8*)(mn + (long)elr[start + i] * 128 + j8);
#pragma unroll
        for (int k = 0; k < 8; ++k) acc[k] += b2f(m[k]);
      }
      float dv = dinv[v];
#pragma unroll
      for (int k = 0; k < 8; ++k) {
        acc[k] = dv * acc[k] + gb[j8 + k];
        ps[k] += acc[k];
        pq[k] += acc[k] * acc[k];
      }
      *(float4*)(agg + (long)v * 128 + j8) = make_float4(acc[0], acc[1], acc[2], acc[3]);
      *(float4*)(agg + (long)v * 128 + j8 + 4) = make_float4(acc[4], acc[5], acc[6], acc[7]);
    }
  }
#pragma unroll
  for (int k = 0; k < 8; ++k) { s_lds[slot][j8 + k] = ps[k]; q_lds[slot][j8 + k] = pq[k]; }
  __syncthreads();
  if (t < 128) {
    float s = 0.f;
#pragma unroll
    for (int sl = 0; sl < 16; ++sl) s += s_lds[sl][t];
    atomicAdd(&sums[t], (double)s);
  } else {
    int j = t - 128;
    float q = 0.f;
#pragma unroll
    for (int sl = 0; sl < 16; ++sl) q += q_lds[sl][j];
    atomicAdd(&sums[128 + j], (double)q);
  }
}

// =============== BN + relu (+ skip) -> bf16 h ===============
template <bool SKIP>
__global__ __launch_bounds__(256) void k_bnskip(
    const float* __restrict__ agg, const double* __restrict__ sums,
    const float* __restrict__ g, const float* __restrict__ b,
    const float* __restrict__ skipv, const float* __restrict__ skipb,
    u16* __restrict__ hb) {
  int idx = blockIdx.x * 256 + threadIdx.x;
  int j = idx & 127;
  double mu = sums[j] * (1.0 / NN);
  double var = sums[128 + j] * (1.0 / NN) - mu * mu;
  float inv = (float)(1.0 / sqrt(var + 1e-5));
  float val = (float)((double)agg[idx] - mu) * inv * g[j] + b[j];
  val = fmaxf(val, 0.f);
  if (SKIP) val += skipv[idx] + skipb[j];
  hb[idx] = f2b(val);
}

// =============== fused per-edge head (all GEMMs on MFMA) ===============
// r8 CSR-ordered structure + register prefetch of the T1 (random rn) side:
// h1 (att input, 128 B) and v1 (cgather input, 256 B) are loaded into registers at
// block top, BEFORE the first barrier. Their ~800cy L3 latency drains at barrier-1
// together with EA staging instead of exposing inside the att / G phases. T2 (cn)
// side stays in-phase (L2-resident after CSR ordering, ~200cy). +64 arch VGPRs —
// safe under (256,2) budget; occupancy already 2 blocks/CU.
#define EPB 128
__global__ __launch_bounds__(256, 2) void k_edge(
    const int* __restrict__ elr, const int* __restrict__ ecn, const int* __restrict__ eid,
    const float* __restrict__ eaf,
    const u16* __restrict__ T1, const u16* __restrict__ T2,
    const float* __restrict__ ee_b1, const float* __restrict__ ee_b2,
    const float* __restrict__ ea_w2, const float* __restrict__ ea_b2,
    const u16* __restrict__ WT_ee1, const u16* __restrict__ WT_eae,
    const u16* __restrict__ WT_ee2, const u16* __restrict__ WT_ab,
    const u16* __restrict__ WT_cl2,
    const float* __restrict__ cl_b2, const float* __restrict__ cl_w3,
    const float* __restrict__ cl_b3,
    float* __restrict__ out) {
  __shared__ u16 ebuf[128 * 128];   // P -> U -> w_ef -> z1 -> z2
  __shared__ u16 ustage[8192];      // EAs[128][32] then 4x per-wave cstage[32][64]
  __shared__ float attP[256];
  __shared__ float attS[128];

  int t = threadIdx.x;
  long ebase = (long)blockIdx.x * EPB;
  int e = t & 127, half = t >> 7;
  int jb0 = half * 64;
  int rn = elr[ebase + e];
  int cn = ecn[ebase + e];

  int l = t & 63, w = t >> 6;
  int wrow = w * 32;
  int cl_ = l & 15, g4 = l >> 4, ko = g4 * 8;

  // per-lane cgather assignment (G phase): lane covers row srow, 32-col quarter cq
  int srow = wrow + (l >> 1);
  int cq = (l & 1) * 32;
  int rs = elr[ebase + srow];
  int cs = ecn[ebase + srow];
  u16* cstage = ustage + w * 2048;  // wave-local 32x64 slice

  // ---- prefetch T1 (random) side into registers; latency drains at barrier-1 ----
  u16x8 h1p[8];
#pragma unroll
  for (int k = 0; k < 8; ++k)
    h1p[k] = *(const u16x8*)(T1 + (long)rn * 256 + jb0 + k * 8);
  u16x8 v1p[8];
#pragma unroll
  for (int k = 0; k < 8; ++k) {
    int hh = k >> 2, kk = k & 3;
    v1p[k] = *(const u16x8*)(T1 + (long)rs * 256 + 128 + hh * 64 + cq + kk * 8);
  }

  // ---- stage EA (zero-padded K=32), gathered via eid ----
  {
    int k0 = half * 16;
    long ge = eid[ebase + e];
    const float* src = eaf + ge * 10;
#pragma unroll
    for (int k = 0; k < 16; ++k) {
      int kk = k0 + k;
      ustage[e * 32 + kk] = (kk < 10) ? f2b(src[kk]) : (u16)0;
    }
  }
  __syncthreads();  // EAs ready (+ prefetch drained)

  // ---- MFMA-P: P = EA @ eaeT -> ebuf (per-nt immediate store) ----
  {
    bf16x8 aEA[2];
#pragma unroll
    for (int mt = 0; mt < 2; ++mt)
      aEA[mt] = *(const bf16x8*)(ustage + (wrow + mt * 16 + cl_) * 32 + ko);
    bf16x8 b[8];
#pragma unroll
    for (int nt = 0; nt < 8; ++nt)
      b[nt] = *(const bf16x8*)(WT_eae + (nt * 16 + cl_) * 32 + ko);
#pragma unroll
    for (int mt = 0; mt < 2; ++mt)
#pragma unroll
      for (int nt = 0; nt < 8; ++nt) {
        f32x4 pa = {0.f, 0.f, 0.f, 0.f};
        pa = __builtin_amdgcn_mfma_f32_16x16x32_bf16(aEA[mt], b[nt], pa, 0, 0, 0);
#pragma unroll
        for (int r = 0; r < 4; ++r) {
          int row = wrow + mt * 16 + g4 * 4 + r;
          int col = nt * 16 + cl_;
          ebuf[row * 128 + (col ^ ((row & 7) * 8))] = f2b(pa[r]);
        }
      }
  }
  __syncthreads();  // P visible

  // ---- att scalar (VALU): sigmoid(relu(h1+h2+P).w2 + b2); h1 from regs ----
  {
    float s = 0.f;
#pragma unroll
    for (int k = 0; k < 8; ++k) {
      int jb = jb0 + k * 8;
      u16x8 h1 = h1p[k];
      u16x8 h2 = *(const u16x8*)(T2 + (long)cn * 256 + jb);
      u16x8 pp = *(const u16x8*)(ebuf + e * 128 + (jb ^ ((e & 7) * 8)));
#pragma unroll
      for (int i = 0; i < 8; ++i)
        s += fmaxf(b2f(h1[i]) + b2f(h2[i]) + b2f(pp[i]), 0.f) * ea_w2[jb + i];
    }
    attP[half * 128 + e] = s;
  }
  __syncthreads();  // attP done; ebuf free

  if (t < 128) attS[t] = 1.f / (1.f + __expf(-(attP[t] + attP[128 + t] + ea_b2[0])));

  // ---- MFMA-U: U = relu(EA @ ee1T + b1) -> ebuf (aEA reloaded; EAs intact) ----
  {
    bf16x8 aEA[2];
#pragma unroll
    for (int mt = 0; mt < 2; ++mt)
      aEA[mt] = *(const bf16x8*)(ustage + (wrow + mt * 16 + cl_) * 32 + ko);
    bf16x8 b[8];
#pragma unroll
    for (int nt = 0; nt < 8; ++nt)
      b[nt] = *(const bf16x8*)(WT_ee1 + (nt * 16 + cl_) * 32 + ko);
#pragma unroll
    for (int mt = 0; mt < 2; ++mt)
#pragma unroll
      for (int nt = 0; nt < 8; ++nt) {
        float bb = ee_b1[nt * 16 + cl_];
        f32x4 ua;
        ua[0] = bb; ua[1] = bb; ua[2] = bb; ua[3] = bb;
        ua = __builtin_amdgcn_mfma_f32_16x16x32_bf16(aEA[mt], b[nt], ua, 0, 0, 0);
#pragma unroll
        for (int r = 0; r < 4; ++r) {
          int row = wrow + mt * 16 + g4 * 4 + r;
          int col = nt * 16 + cl_;
          ebuf[row * 128 + (col ^ ((row & 7) * 8))] = f2b(fmaxf(ua[r], 0.f));
        }
      }
  }
  __syncthreads();  // attS visible to all (U is wave-local)

  // ---- eeL2: F = U @ ee_w2 + b2 ; w_ef = att*F -> ebuf (nt-halved, A hoisted) ----
  {
    bf16x8 a2[4][2];
#pragma unroll
    for (int c = 0; c < 4; ++c)
#pragma unroll
      for (int mt = 0; mt < 2; ++mt) {
        int row = wrow + mt * 16 + cl_;
        a2[c][mt] = *(const bf16x8*)(ebuf + row * 128 + ((c * 32 + ko) ^ ((row & 7) * 8)));
      }
#pragma unroll
    for (int hh = 0; hh < 2; ++hh) {
      f32x4 acc[2][4];
#pragma unroll
      for (int n4 = 0; n4 < 4; ++n4) {
        float bb = ee_b2[(hh * 4 + n4) * 16 + cl_];
#pragma unroll
        for (int mt = 0; mt < 2; ++mt) { acc[mt][n4][0] = bb; acc[mt][n4][1] = bb; acc[mt][n4][2] = bb; acc[mt][n4][3] = bb; }
      }
#pragma unroll
      for (int c = 0; c < 4; ++c)
#pragma unroll
        for (int n4 = 0; n4 < 4; ++n4) {
          bf16x8 b = *(const bf16x8*)(WT_ee2 + ((hh * 4 + n4) * 16 + cl_) * 128 + c * 32 + ko);
#pragma unroll
          for (int mt = 0; mt < 2; ++mt)
            acc[mt][n4] = __builtin_amdgcn_mfma_f32_16x16x32_bf16(a2[c][mt], b, acc[mt][n4], 0, 0, 0);
        }
#pragma unroll
      for (int mt = 0; mt < 2; ++mt)
#pragma unroll
        for (int r = 0; r < 4; ++r) {
          int row = wrow + mt * 16 + g4 * 4 + r;
          float av = attS[row];
#pragma unroll
          for (int n4 = 0; n4 < 4; ++n4) {
            int col = (hh * 4 + n4) * 16 + cl_;
            ebuf[row * 128 + (col ^ ((row & 7) * 8))] = f2b(av * acc[mt][n4][r]);
          }
        }
    }
  }

  // ---- G: g = w_ef @ Wab ; z1 = relu(cn1[rn]+cn2[cn] + g) -> ebuf (nt-halved) ----
  {
    bf16x8 a2[4][2];
#pragma unroll
    for (int c = 0; c < 4; ++c)
#pragma unroll
      for (int mt = 0; mt < 2; ++mt) {
        int row = wrow + mt * 16 + cl_;
        a2[c][mt] = *(const bf16x8*)(ebuf + row * 128 + ((c * 32 + ko) ^ ((row & 7) * 8)));
      }
#pragma unroll
    for (int hh = 0; hh < 2; ++hh) {
      f32x4 acc[2][4];
#pragma unroll
      for (int n4 = 0; n4 < 4; ++n4)
#pragma unroll
        for (int mt = 0; mt < 2; ++mt) { acc[mt][n4][0] = 0.f; acc[mt][n4][1] = 0.f; acc[mt][n4][2] = 0.f; acc[mt][n4][3] = 0.f; }
#pragma unroll
      for (int c = 0; c < 4; ++c)
#pragma unroll
        for (int n4 = 0; n4 < 4; ++n4) {
          bf16x8 b = *(const bf16x8*)(WT_ab + ((hh * 4 + n4) * 16 + cl_) * 128 + c * 32 + ko);
#pragma unroll
          for (int mt = 0; mt < 2; ++mt)
            acc[mt][n4] = __builtin_amdgcn_mfma_f32_16x16x32_bf16(a2[c][mt], b, acc[mt][n4], 0, 0, 0);
        }
      // wave-local cgather: v1 from prefetched regs, v2 (L2-resident) in-phase
      u16x8 v2[4];
#pragma unroll
      for (int k = 0; k < 4; ++k)
        v2[k] = *(const u16x8*)(T2 + (long)cs * 256 + 128 + hh * 64 + cq + k * 8);
#pragma unroll
      for (int k = 0; k < 4; ++k) {
        u16x8 p;
#pragma unroll
        for (int i = 0; i < 8; ++i) p[i] = f2b(b2f(v1p[hh * 4 + k][i]) + b2f(v2[k][i]));
        *(u16x8*)(cstage + (srow & 31) * 64 + ((cq + k * 8) ^ ((srow & 7) * 8))) = p;
      }
#pragma unroll
      for (int mt = 0; mt < 2; ++mt)
#pragma unroll
        for (int r = 0; r < 4; ++r) {
          int row = wrow + mt * 16 + g4 * 4 + r;
#pragma unroll
          for (int n4 = 0; n4 < 4; ++n4) {
            int col = (hh * 4 + n4) * 16 + cl_;
            int cc = col - hh * 64;
            float v = acc[mt][n4][r] + b2f(cstage[(row & 31) * 64 + (cc ^ ((row & 7) * 8))]);
            ebuf[row * 128 + (col ^ ((row & 7) * 8))] = f2b(fmaxf(v, 0.f));
          }
        }
    }
  }

  // ---- clL2: z2 = relu(z1 @ cl_w2 + b2) (N=64) ----
  f32x4 acc2[2][4];
#pragma unroll
  for (int nt = 0; nt < 4; ++nt) {
    float bb = cl_b2[nt * 16 + cl_];
#pragma unroll
    for (int mt = 0; mt < 2; ++mt) { acc2[mt][nt][0] = bb; acc2[mt][nt][1] = bb; acc2[mt][nt][2] = bb; acc2[mt][nt][3] = bb; }
  }
#pragma unroll
  for (int c = 0; c < 4; ++c) {
    bf16x8 a[2], b[4];
#pragma unroll
    for (int mt = 0; mt < 2; ++mt) {
      int row = wrow + mt * 16 + cl_;
      a[mt] = *(const bf16x8*)(ebuf + row * 128 + ((c * 32 + ko) ^ ((row & 7) * 8)));
    }
#pragma unroll
    for (int nt = 0; nt < 4; ++nt)
      b[nt] = *(const bf16x8*)(WT_cl2 + (nt * 16 + cl_) * 128 + c * 32 + ko);
#pragma unroll
    for (int mt = 0; mt < 2; ++mt)
#pragma unroll
      for (int nt = 0; nt < 4; ++nt)
        acc2[mt][nt] = __builtin_amdgcn_mfma_f32_16x16x32_bf16(a[mt], b[nt], acc2[mt][nt], 0, 0, 0);
  }
#pragma unroll
  for (int mt = 0; mt < 2; ++mt)
#pragma unroll
    for (int r = 0; r < 4; ++r) {
      int row = wrow + mt * 16 + g4 * 4 + r;
#pragma unroll
      for (int nt = 0; nt < 4; ++nt) {
        int col = nt * 16 + cl_;
        ebuf[row * 128 + (col ^ ((row & 7) * 8))] = f2b(fmaxf(acc2[mt][nt][r], 0.f));
      }
    }
  __syncthreads();

  // ---- clL3: scatter to original edge order via eid ----
  if (t < 128) {
    long ge = eid[ebase + t];
    float o0 = cl_b3[0], o1 = cl_b3[1];
    for (int k8 = 0; k8 < 64; k8 += 8) {
      u16x8 v = *(const u16x8*)(ebuf + t * 128 + (k8 ^ ((t & 7) * 8)));
#pragma unroll
      for (int i = 0; i < 8; ++i) {
        float z = b2f(v[i]);
        o0 += z * cl_w3[(k8 + i) * 2];
        o1 += z * cl_w3[(k8 + i) * 2 + 1];
      }
    }
    *(float2*)(out + ge * 2) = make_float2(o0, o1);
  }
}

extern "C" void kernel_launch(void* const* d_in, const int* in_sizes, int n_in,
                              void* d_out, int out_size, void* d_ws, size_t ws_size,
                              hipStream_t stream) {
  (void)in_sizes; (void)n_in; (void)out_size; (void)ws_size;
  const float* x = (const float*)d_in[0];
  const int* ei = (const int*)d_in[1];
  const float* eattr = (const float*)d_in[2];
  const float* ne_w1 = (const float*)d_in[3];
  const float* ne_b1 = (const float*)d_in[4];
  const float* ne_w2 = (const float*)d_in[5];
  const float* ne_b2 = (const float*)d_in[6];
  const float* ee_w1 = (const float*)d_in[7];
  const float* ee_b1 = (const float*)d_in[8];
  const float* ee_w2 = (const float*)d_in[9];
  const float* ee_b2 = (const float*)d_in[10];
  const float* ea_w1 = (const float*)d_in[11];
  const float* ea_b1 = (const float*)d_in[12];
  const float* ea_w2 = (const float*)d_in[13];
  const float* ea_b2 = (const float*)d_in[14];
  const float* gcn_w = (const float*)d_in[15];
  const float* gcn_b = (const float*)d_in[16];
  const float* bn_g = (const float*)d_in[17];
  const float* bn_b = (const float*)d_in[18];
  const float* skip_w = (const float*)d_in[19];
  const float* skip_b = (const float*)d_in[20];
  const float* cl_w1 = (const float*)d_in[21];
  const float* cl_b1 = (const float*)d_in[22];
  const float* cl_w2 = (const float*)d_in[23];
  const float* cl_b2 = (const float*)d_in[24];
  const float* cl_w3 = (const float*)d_in[25];
  const float* cl_b3 = (const float*)d_in[26];
  float* out = (float*)d_out;

  // ws layout (bytes)
  char* ws = (char*)d_ws;
  u16* hb0 = (u16*)ws;                              // 12.8e6
  u16* hb1 = (u16*)(ws + 12800000);                 // 12.8e6
  float* A = (float*)(ws + 25600000);               // 25.6e6 f32 (skip out) / T1 overlay
  u16* mn = (u16*)(ws + 51200000);                  // 12.8e6 bf16 scaled message
  float* agg = (float*)(ws + 64000000);             // 25.6e6 / T2 overlay
  unsigned* deg = (unsigned*)(ws + 89600000);       // 200e3
  float* dinv = (float*)(ws + 89800000);            // 200e3
  double* sums = (double*)(ws + 90000000);          // 2048
  u16* WP = (u16*)(ws + 90002048);                  // 425984 B
  int* offs = (int*)(ws + 90428032);                // 200e3
  int* cursor = (int*)(ws + 90628032);              // 200e3
  int* bsum = (int*)(ws + 90828032);                // 1024
  int* boff = (int*)(ws + 90829056);                // 1024
  int* elr = (int*)(ws + 90830080);                 // 3.2e6
  int* ecn = (int*)(ws + 94030080);                 // 3.2e6
  int* eid = (int*)(ws + 97230080);                 // 3.2e6 (end ~100.4 MB)
  u16* T1 = (u16*)A;
  u16* T2 = (u16*)agg;

  u16* WP_ne2 = WP;
  u16* WP_gcn = WP + 16384;
  u16* WP_skip = WP + 65536;
  u16* WP_t4 = WP + 98304;
  u16* WP_ab = WP + 163840;
  u16* WP_ee2 = WP + 180224;
  u16* WP_cl2 = WP + 196608;
  u16* WP_ee1 = WP + 204800;
  u16* WP_eae = WP + 208896;

  const int* col = ei + NE;
  const int NGB = (NN + 255) / 256;   // 196 (scan kernels)
  const int NGB128 = (NN + 127) / 128; // 391 (BM=128 GEMMs)

  k_prep<<<832, 256, 0, stream>>>(ea_w1, cl_w1, ee_w2, cl_w2, gcn_w, skip_w, ne_w2, ee_w1, WP);
  hipMemsetAsync(deg, 0, NN * sizeof(unsigned), stream);
  k_deg<<<(NE + 255) / 256, 256, 0, stream>>>(col, deg);
  k_scan1<<<NGB, 256, 0, stream>>>(deg, bsum);
  k_scan2<<<1, 256, 0, stream>>>(bsum, boff, NGB);
  k_scan3<<<NGB, 256, 0, stream>>>(deg, boff, offs, cursor, dinv);
  k_fill<<<(NE + 255) / 256, 256, 0, stream>>>(ei, cursor, elr, ecn, eid);

  k_rowenc<<<NN / 16, 256, 0, stream>>>(x, ne_w1, ne_b1, hb1);
  k_ngemm<<<NGB128, 256, 0, stream>>>(hb1, WP_ne2, ne_b2, hb0);

  u16* hin = hb0; u16* hout = hb1;
  for (int i = 0; i < 3; ++i) {
    if (i > 0)
      k_gcnskip<<<dim3(NGB128, 2), 256, 0, stream>>>(hin, WP_gcn + (long)i * 16384,
                                                     WP_skip + (long)(i - 1) * 16384, dinv, mn, A);
    else
      k_gcnskip<<<dim3(NGB128, 1), 256, 0, stream>>>(hin, WP_gcn, nullptr, dinv, mn, nullptr);
    hipMemsetAsync(sums, 0, 256 * sizeof(double), stream);
    k_agg<<<(NN + 63) / 64, 256, 0, stream>>>(offs, deg, elr, dinv, mn, gcn_b + i * H, agg, sums);
    if (i > 0)
      k_bnskip<true><<<NN * H / 256, 256, 0, stream>>>(
          agg, sums, bn_g + i * H, bn_b + i * H, A, skip_b + (i - 1) * H, hout);
    else
      k_bnskip<false><<<NN * H / 256, 256, 0, stream>>>(
          agg, sums, bn_g, bn_b, nullptr, nullptr, hout);
    u16* tmp = hin; hin = hout; hout = tmp;
  }

  k_ntab<<<dim3(NGB128, 4), 256, 0, stream>>>(hin, WP_t4, ea_b1, cl_b1, T1, T2);

  k_edge<<<NE / EPB, 256, 0, stream>>>(
      elr, ecn, eid, eattr, T1, T2, ee_b1, ee_b2, ea_w2, ea_b2,
      WP_ee1, WP_eae, WP_ee2, WP_ab, WP_cl2, cl_b2, cl_w3, cl_b3, out);
}

// Round 10
// 884.227 us; speedup vs baseline: 1.0259x; 1.0259x over previous
//
#include <hip/hip_runtime.h>
#include <math.h>

#define NN 50000
#define NE 800000
#define H 128

typedef short bf16x8 __attribute__((ext_vector_type(8)));
typedef unsigned short u16x8 __attribute__((ext_vector_type(8)));
typedef float f32x4 __attribute__((ext_vector_type(4)));
typedef unsigned short u16;

__device__ inline u16 f2b(float f) {
  unsigned u = __float_as_uint(f);
  return (u16)((u + 0x7FFF + ((u >> 16) & 1)) >> 16);
}
__device__ inline float b2f(u16 s) { return __uint_as_float(((unsigned)s) << 16); }

// =============== weight prep: bf16, transposed WT[n][k] = W[k][n] ===============
// WP element offsets:
//   ne2:0 gcn:16384(x3) skip:65536(x2)
//   t4:98304 (hn1,cn1,hn2,cn2 each 16384)
//   ab:163840 ee2:180224 cl2:196608(8192) ee1:204800([128][32]) eae:208896([128][32])
//   ne1:212992([128][32] zero-padded K, for fused node encoder) end:217088
__global__ void k_prep(const float* __restrict__ ea_w1, const float* __restrict__ cl_w1,
                       const float* __restrict__ ee_w2, const float* __restrict__ cl_w2,
                       const float* __restrict__ gcn_w, const float* __restrict__ skip_w,
                       const float* __restrict__ ne_w2, const float* __restrict__ ee_w1,
                       const float* __restrict__ ne_w1, u16* __restrict__ WP) {
  int idx = blockIdx.x * 256 + threadIdx.x;
  if (idx >= 217088) return;
  float v;
  if (idx < 16384) {            // ne2
    int n = idx >> 7, k = idx & 127;
    v = ne_w2[k * 128 + n];
  } else if (idx < 65536) {     // gcn
    int lo = idx - 16384; int i = lo >> 14; int n = (lo >> 7) & 127, k = lo & 127;
    v = gcn_w[i * 16384 + k * 128 + n];
  } else if (idx < 98304) {     // skip
    int lo = idx - 65536; int i = lo >> 14; int n = (lo >> 7) & 127, k = lo & 127;
    v = skip_w[i * 16384 + k * 128 + n];
  } else if (idx < 163840) {    // t4: hn1, cn1, hn2, cn2
    int lo = idx - 98304; int tab = lo >> 14; int n = (lo >> 7) & 127, k = lo & 127;
    if (tab == 0) v = ea_w1[k * 128 + n];
    else if (tab == 1) v = cl_w1[k * 128 + n];
    else if (tab == 2) v = ea_w1[(128 + k) * 128 + n];
    else v = cl_w1[(128 + k) * 128 + n];
  } else if (idx < 180224) {    // ab
    int lo = idx - 163840; int n = lo >> 7, k = lo & 127;
    v = cl_w1[k * 128 + n] + cl_w1[(128 + k) * 128 + n];
  } else if (idx < 196608) {    // ee2
    int lo = idx - 180224; int n = lo >> 7, k = lo & 127;
    v = ee_w2[k * 128 + n];
  } else if (idx < 204800) {    // cl2 [64][128]
    int lo = idx - 196608; int n = lo >> 7, k = lo & 127;
    v = cl_w2[k * 64 + n];
  } else if (idx < 208896) {    // ee1 [128][32] zero-padded K
    int lo = idx - 204800; int n = lo >> 5, k = lo & 31;
    v = (k < 10) ? ee_w1[k * 128 + n] : 0.f;
  } else if (idx < 212992) {    // eae [128][32] zero-padded K (ea_w1 rows 256..265)
    int lo = idx - 208896; int n = lo >> 5, k = lo & 31;
    v = (k < 10) ? ea_w1[(256 + k) * 128 + n] : 0.f;
  } else {                      // ne1 [128][32] zero-padded K
    int lo = idx - 212992; int n = lo >> 5, k = lo & 31;
    v = (k < 10) ? ne_w1[k * 128 + n] : 0.f;
  }
  WP[idx] = f2b(v);
}

// =============== fused node encoder: hb0 = relu(x@ne_w1+b1) @ ne_w2 + b2 ===============
// L1 via K=32-padded MFMA (k_edge EA-staging pattern) directly into the swizzled As
// tile; L2 = standard K=128 loop. Kills k_rowenc + the 25.6 MB hb1 round-trip.
// L1->L2 As dependency is wave-local (each wave reads only its own 32 rows).
__global__ __launch_bounds__(256, 2) void k_nodeenc(
    const float* __restrict__ x, const u16* __restrict__ WT1,
    const u16* __restrict__ WT2, const float* __restrict__ b1,
    const float* __restrict__ b2, u16* __restrict__ outB) {
  __shared__ u16 XL[128 * 32];
  __shared__ u16 As[128 * 128];
  int t = threadIdx.x;
  long base = (long)blockIdx.x * 128;
  for (int idx = t; idx < 128 * 32; idx += 256) {
    int row = idx >> 5, kk = idx & 31;
    long gr = base + row; if (gr >= NN) gr = 0;
    XL[idx] = (kk < 10) ? f2b(x[gr * 10 + kk]) : (u16)0;
  }
  __syncthreads();
  int l = t & 63, w = t >> 6;
  int wrow = w * 32;
  int cl_ = l & 15, g4 = l >> 4, ko = g4 * 8;
  // ---- L1: u = relu(x @ ne_w1 + b1) -> As (swizzled bf16) ----
  {
    bf16x8 a[2], b[8];
#pragma unroll
    for (int mt = 0; mt < 2; ++mt)
      a[mt] = *(const bf16x8*)(XL + (wrow + mt * 16 + cl_) * 32 + ko);
#pragma unroll
    for (int nt = 0; nt < 8; ++nt)
      b[nt] = *(const bf16x8*)(WT1 + (nt * 16 + cl_) * 32 + ko);
#pragma unroll
    for (int mt = 0; mt < 2; ++mt)
#pragma unroll
      for (int nt = 0; nt < 8; ++nt) {
        float bb = b1[nt * 16 + cl_];
        f32x4 ua;
        ua[0] = bb; ua[1] = bb; ua[2] = bb; ua[3] = bb;
        ua = __builtin_amdgcn_mfma_f32_16x16x32_bf16(a[mt], b[nt], ua, 0, 0, 0);
#pragma unroll
        for (int r = 0; r < 4; ++r) {
          int row = wrow + mt * 16 + g4 * 4 + r;
          int col = nt * 16 + cl_;
          As[row * 128 + (col ^ ((row & 7) * 8))] = f2b(fmaxf(ua[r], 0.f));
        }
      }
  }
  // ---- L2: out = u @ ne_w2 + b2 (wave-local As rows) ----
  f32x4 acc[2][8];
#pragma unroll
  for (int nt = 0; nt < 8; ++nt) {
    float bb = b2[nt * 16 + cl_];
#pragma unroll
    for (int mt = 0; mt < 2; ++mt) { acc[mt][nt][0] = bb; acc[mt][nt][1] = bb; acc[mt][nt][2] = bb; acc[mt][nt][3] = bb; }
  }
#pragma unroll
  for (int c = 0; c < 4; ++c) {
    bf16x8 a[2], b[8];
#pragma unroll
    for (int mt = 0; mt < 2; ++mt) {
      int row = wrow + mt * 16 + cl_;
      a[mt] = *(const bf16x8*)(As + row * 128 + ((c * 32 + ko) ^ ((row & 7) * 8)));
    }
#pragma unroll
    for (int nt = 0; nt < 8; ++nt)
      b[nt] = *(const bf16x8*)(WT2 + (nt * 16 + cl_) * 128 + c * 32 + ko);
#pragma unroll
    for (int mt = 0; mt < 2; ++mt)
#pragma unroll
      for (int nt = 0; nt < 8; ++nt)
        acc[mt][nt] = __builtin_amdgcn_mfma_f32_16x16x32_bf16(a[mt], b[nt], acc[mt][nt], 0, 0, 0);
  }
#pragma unroll
  for (int mt = 0; mt < 2; ++mt)
#pragma unroll
    for (int r = 0; r < 4; ++r) {
      long row = base + wrow + mt * 16 + g4 * 4 + r;
      if (row >= NN) continue;
#pragma unroll
      for (int nt = 0; nt < 8; ++nt)
        outB[row * 128 + nt * 16 + cl_] = f2b(acc[mt][nt][r]);
    }
}

// =============== gcn(+skip) GEMM, merged: one stage, two weight tables ===============
__global__ __launch_bounds__(256, 2) void k_gcnskip(
    const u16* __restrict__ Ain, const u16* __restrict__ WTg, const u16* __restrict__ WTs,
    const float* __restrict__ dinv, u16* __restrict__ mn, float* __restrict__ Af) {
  __shared__ u16 As[128 * 128];
  int t = threadIdx.x;
  long base = (long)blockIdx.x * 128;
  for (int idx = t; idx < 128 * 16; idx += 256) {
    int row = idx >> 4, k8 = (idx & 15) * 8;
    long gr = base + row; if (gr >= NN) gr = 0;
    uint4 v = *(const uint4*)(Ain + gr * 128 + k8);
    *(uint4*)(As + row * 128 + (k8 ^ ((row & 7) * 8))) = v;
  }
  __syncthreads();
  int l = t & 63, w = t >> 6;
  int wrow = w * 32;
  int cl_ = l & 15, g4 = l >> 4, ko = g4 * 8;
  // pass 1: gcn -> mn (dinv-premultiplied bf16)
  {
    f32x4 acc[2][8];
#pragma unroll
    for (int nt = 0; nt < 8; ++nt)
#pragma unroll
      for (int mt = 0; mt < 2; ++mt) { acc[mt][nt][0] = 0.f; acc[mt][nt][1] = 0.f; acc[mt][nt][2] = 0.f; acc[mt][nt][3] = 0.f; }
#pragma unroll
    for (int c = 0; c < 4; ++c) {
      bf16x8 a[2], b[8];
#pragma unroll
      for (int mt = 0; mt < 2; ++mt) {
        int row = wrow + mt * 16 + cl_;
        a[mt] = *(const bf16x8*)(As + row * 128 + ((c * 32 + ko) ^ ((row & 7) * 8)));
      }
#pragma unroll
      for (int nt = 0; nt < 8; ++nt)
        b[nt] = *(const bf16x8*)(WTg + (nt * 16 + cl_) * 128 + c * 32 + ko);
#pragma unroll
      for (int mt = 0; mt < 2; ++mt)
#pragma unroll
        for (int nt = 0; nt < 8; ++nt)
          acc[mt][nt] = __builtin_amdgcn_mfma_f32_16x16x32_bf16(a[mt], b[nt], acc[mt][nt], 0, 0, 0);
    }
#pragma unroll
    for (int mt = 0; mt < 2; ++mt)
#pragma unroll
      for (int r = 0; r < 4; ++r) {
        long row = base + wrow + mt * 16 + g4 * 4 + r;
        if (row >= NN) continue;
        float dv = dinv[row];
#pragma unroll
        for (int nt = 0; nt < 8; ++nt)
          mn[row * 128 + nt * 16 + cl_] = f2b(dv * acc[mt][nt][r]);
      }
  }
  // pass 2: skip -> Af (f32); As read-only, no barrier needed
  if (WTs) {
    f32x4 acc[2][8];
#pragma unroll
    for (int nt = 0; nt < 8; ++nt)
#pragma unroll
      for (int mt = 0; mt < 2; ++mt) { acc[mt][nt][0] = 0.f; acc[mt][nt][1] = 0.f; acc[mt][nt][2] = 0.f; acc[mt][nt][3] = 0.f; }
#pragma unroll
    for (int c = 0; c < 4; ++c) {
      bf16x8 a[2], b[8];
#pragma unroll
      for (int mt = 0; mt < 2; ++mt) {
        int row = wrow + mt * 16 + cl_;
        a[mt] = *(const bf16x8*)(As + row * 128 + ((c * 32 + ko) ^ ((row & 7) * 8)));
      }
#pragma unroll
      for (int nt = 0; nt < 8; ++nt)
        b[nt] = *(const bf16x8*)(WTs + (nt * 16 + cl_) * 128 + c * 32 + ko);
#pragma unroll
      for (int mt = 0; mt < 2; ++mt)
#pragma unroll
        for (int nt = 0; nt < 8; ++nt)
          acc[mt][nt] = __builtin_amdgcn_mfma_f32_16x16x32_bf16(a[mt], b[nt], acc[mt][nt], 0, 0, 0);
    }
#pragma unroll
    for (int mt = 0; mt < 2; ++mt)
#pragma unroll
      for (int r = 0; r < 4; ++r) {
        long row = base + wrow + mt * 16 + g4 * 4 + r;
        if (row >= NN) continue;
#pragma unroll
        for (int nt = 0; nt < 8; ++nt)
          Af[row * 128 + nt * 16 + cl_] = acc[mt][nt][r];
      }
  }
}

// =============== 4-table GEMM, merged: one stage, four weight tables ===============
__global__ __launch_bounds__(256, 2) void k_ntab(
    const u16* __restrict__ A, const u16* __restrict__ WPt4,
    const float* __restrict__ ea_b1, const float* __restrict__ cl_b1,
    u16* __restrict__ T1, u16* __restrict__ T2) {
  __shared__ u16 As[128 * 128];
  int t = threadIdx.x;
  long base = (long)blockIdx.x * 128;
  for (int idx = t; idx < 128 * 16; idx += 256) {
    int row = idx >> 4, k8 = (idx & 15) * 8;
    long gr = base + row; if (gr >= NN) gr = 0;
    uint4 v = *(const uint4*)(A + gr * 128 + k8);
    *(uint4*)(As + row * 128 + (k8 ^ ((row & 7) * 8))) = v;
  }
  __syncthreads();
  int l = t & 63, w = t >> 6;
  int wrow = w * 32;
  int cl_ = l & 15, g4 = l >> 4, ko = g4 * 8;
  for (int y = 0; y < 4; ++y) {
    const u16* WT = WPt4 + y * 16384;
    const float* bias = (y == 0) ? ea_b1 : ((y == 1) ? cl_b1 : nullptr);
    u16* outT = (y < 2) ? T1 : T2;
    int colOff = (y & 1) * 128;
    f32x4 acc[2][8];
#pragma unroll
    for (int nt = 0; nt < 8; ++nt) {
      float bb = bias ? bias[nt * 16 + cl_] : 0.f;
#pragma unroll
      for (int mt = 0; mt < 2; ++mt) { acc[mt][nt][0] = bb; acc[mt][nt][1] = bb; acc[mt][nt][2] = bb; acc[mt][nt][3] = bb; }
    }
#pragma unroll
    for (int c = 0; c < 4; ++c) {
      bf16x8 a[2], b[8];
#pragma unroll
      for (int mt = 0; mt < 2; ++mt) {
        int row = wrow + mt * 16 + cl_;
        a[mt] = *(const bf16x8*)(As + row * 128 + ((c * 32 + ko) ^ ((row & 7) * 8)));
      }
#pragma unroll
      for (int nt = 0; nt < 8; ++nt)
        b[nt] = *(const bf16x8*)(WT + (nt * 16 + cl_) * 128 + c * 32 + ko);
#pragma unroll
      for (int mt = 0; mt < 2; ++mt)
#pragma unroll
        for (int nt = 0; nt < 8; ++nt)
          acc[mt][nt] = __builtin_amdgcn_mfma_f32_16x16x32_bf16(a[mt], b[nt], acc[mt][nt], 0, 0, 0);
    }
#pragma unroll
    for (int mt = 0; mt < 2; ++mt)
#pragma unroll
      for (int r = 0; r < 4; ++r) {
        long row = base + wrow + mt * 16 + g4 * 4 + r;
        if (row >= NN) continue;
#pragma unroll
        for (int nt = 0; nt < 8; ++nt)
          outT[row * 256 + colOff + nt * 16 + cl_] = f2b(acc[mt][nt][r]);
      }
  }
}

// =============== degree ===============
__global__ void k_deg(const int* __restrict__ col, unsigned* __restrict__ deg) {
  int e = blockIdx.x * 256 + threadIdx.x;
  if (e < NE) atomicAdd(&deg[col[e]], 1u);
}

// =============== CSR build ===============
__global__ __launch_bounds__(256) void k_scan1(const unsigned* __restrict__ deg,
                                               int* __restrict__ bsum) {
  __shared__ int s[256];
  int t = threadIdx.x, v = blockIdx.x * 256 + t;
  s[t] = (v < NN) ? (int)deg[v] : 0;
  __syncthreads();
  for (int off = 128; off > 0; off >>= 1) {
    if (t < off) s[t] += s[t + off];
    __syncthreads();
  }
  if (t == 0) bsum[blockIdx.x] = s[0];
}
__global__ __launch_bounds__(256) void k_scan2(const int* __restrict__ bsum,
                                               int* __restrict__ boff, int nb) {
  __shared__ int s[256];
  int t = threadIdx.x;
  int v = (t < nb) ? bsum[t] : 0;
  s[t] = v;
  __syncthreads();
  for (int off = 1; off < 256; off <<= 1) {
    int x = (t >= off) ? s[t - off] : 0;
    __syncthreads();
    s[t] += x;
    __syncthreads();
  }
  if (t < nb) boff[t] = s[t] - v;
}
__global__ __launch_bounds__(256) void k_scan3(const unsigned* __restrict__ deg,
                                               const int* __restrict__ boff,
                                               int* __restrict__ offs, int* __restrict__ cursor,
                                               float* __restrict__ dinv) {
  __shared__ int s[256];
  int t = threadIdx.x, v = blockIdx.x * 256 + t;
  int d = (v < NN) ? (int)deg[v] : 0;
  s[t] = d;
  __syncthreads();
  for (int off = 1; off < 256; off <<= 1) {
    int x = (t >= off) ? s[t - off] : 0;
    __syncthreads();
    s[t] += x;
    __syncthreads();
  }
  int excl = s[t] - d + boff[blockIdx.x];
  if (v < NN) {
    offs[v] = excl; cursor[v] = excl;
    dinv[v] = 1.0f / sqrtf((float)(d + 1));
  }
}
__global__ void k_fill(const int* __restrict__ ei, int* __restrict__ cursor,
                       int* __restrict__ elr, int* __restrict__ ecn, int* __restrict__ eid) {
  int e = blockIdx.x * 256 + threadIdx.x;
  if (e < NE) {
    int c = ei[NE + e];
    int pos = atomicAdd(&cursor[c], 1);
    elr[pos] = ei[e];
    ecn[pos] = c;
    eid[pos] = e;
  }
}

// =============== CSR aggregate + fused BN stats ===============
__global__ __launch_bounds__(256) void k_agg(
    const int* __restrict__ offs, const unsigned* __restrict__ deg,
    const int* __restrict__ elr, const float* __restrict__ dinv,
    const u16* __restrict__ mn, const float* __restrict__ gb,
    float* __restrict__ agg, double* __restrict__ sums) {
  __shared__ float s_lds[16][128];
  __shared__ float q_lds[16][128];
  int t = threadIdx.x;
  int slot = t >> 4;
  int j8 = (t & 15) * 8;
  float ps[8], pq[8];
#pragma unroll
  for (int k = 0; k < 8; ++k) { ps[k] = 0.f; pq[k] = 0.f; }
  int vbase = blockIdx.x * 64;
  for (int nn = 0; nn < 4; ++nn) {
    int v = vbase + nn * 16 + slot;
    if (v < NN) {
      float acc[8];
      u16x8 m0 = *(const u16x8*)(mn + (long)v * 128 + j8);
#pragma unroll
      for (int k = 0; k < 8; ++k) acc[k] = b2f(m0[k]);
      int start = offs[v];
      int cnt = (int)deg[v];
      for (int i = 0; i < cnt; ++i) {
        u16x8 m = *(const u16x8*)(mn + (long)elr[start + i] * 128 + j8);
#pragma unroll
        for (int k = 0; k < 8; ++k) acc[k] += b2f(m[k]);
      }
      float dv = dinv[v];
#pragma unroll
      for (int k = 0; k < 8; ++k) {
        acc[k] = dv * acc[k] + gb[j8 + k];
        ps[k] += acc[k];
        pq[k] += acc[k] * acc[k];
      }
      *(float4*)(agg + (long)v * 128 + j8) = make_float4(acc[0], acc[1], acc[2], acc[3]);
      *(float4*)(agg + (long)v * 128 + j8 + 4) = make_float4(acc[4], acc[5], acc[6], acc[7]);
    }
  }
#pragma unroll
  for (int k = 0; k < 8; ++k) { s_lds[slot][j8 + k] = ps[k]; q_lds[slot][j8 + k] = pq[k]; }
  __syncthreads();
  if (t < 128) {
    float s = 0.f;
#pragma unroll
    for (int sl = 0; sl < 16; ++sl) s += s_lds[sl][t];
    atomicAdd(&sums[t], (double)s);
  } else {
    int j = t - 128;
    float q = 0.f;
#pragma unroll
    for (int sl = 0; sl < 16; ++sl) q += q_lds[sl][j];
    atomicAdd(&sums[128 + j], (double)q);
  }
}

// =============== BN + relu (+ skip) -> bf16 h ===============
template <bool SKIP>
__global__ __launch_bounds__(256) void k_bnskip(
    const float* __restrict__ agg, const double* __restrict__ sums,
    const float* __restrict__ g, const float* __restrict__ b,
    const float* __restrict__ skipv, const float* __restrict__ skipb,
    u16* __restrict__ hb) {
  int idx = blockIdx.x * 256 + threadIdx.x;
  int j = idx & 127;
  double mu = sums[j] * (1.0 / NN);
  double var = sums[128 + j] * (1.0 / NN) - mu * mu;
  float inv = (float)(1.0 / sqrt(var + 1e-5));
  float val = (float)((double)agg[idx] - mu) * inv * g[j] + b[j];
  val = fmaxf(val, 0.f);
  if (SKIP) val += skipv[idx] + skipb[j];
  hb[idx] = f2b(val);
}

// =============== fused per-edge head (all GEMMs on MFMA) ===============
// EXACT r8 structure (413 us): CSR-ordered edges (T2-side L2-resident), register-lean
// phases, NO T1 prefetch (r9: +8 us, +20 MB FETCH — reverted).
#define EPB 128
__global__ __launch_bounds__(256, 2) void k_edge(
    const int* __restrict__ elr, const int* __restrict__ ecn, const int* __restrict__ eid,
    const float* __restrict__ eaf,
    const u16* __restrict__ T1, const u16* __restrict__ T2,
    const float* __restrict__ ee_b1, const float* __restrict__ ee_b2,
    const float* __restrict__ ea_w2, const float* __restrict__ ea_b2,
    const u16* __restrict__ WT_ee1, const u16* __restrict__ WT_eae,
    const u16* __restrict__ WT_ee2, const u16* __restrict__ WT_ab,
    const u16* __restrict__ WT_cl2,
    const float* __restrict__ cl_b2, const float* __restrict__ cl_w3,
    const float* __restrict__ cl_b3,
    float* __restrict__ out) {
  __shared__ u16 ebuf[128 * 128];   // P -> U -> w_ef -> z1 -> z2
  __shared__ u16 ustage[8192];      // EAs[128][32] then 4x per-wave cstage[32][64]
  __shared__ float attP[256];
  __shared__ float attS[128];

  int t = threadIdx.x;
  long ebase = (long)blockIdx.x * EPB;
  int e = t & 127, half = t >> 7;
  int jb0 = half * 64;
  int rn = elr[ebase + e];
  int cn = ecn[ebase + e];

  int l = t & 63, w = t >> 6;
  int wrow = w * 32;
  int cl_ = l & 15, g4 = l >> 4, ko = g4 * 8;

  int srow = wrow + (l >> 1);
  int cq = (l & 1) * 32;
  int rs = elr[ebase + srow];
  int cs = ecn[ebase + srow];
  u16* cstage = ustage + w * 2048;  // wave-local 32x64 slice

  // ---- stage EA (zero-padded K=32), gathered via eid ----
  {
    int k0 = half * 16;
    long ge = eid[ebase + e];
    const float* src = eaf + ge * 10;
#pragma unroll
    for (int k = 0; k < 16; ++k) {
      int kk = k0 + k;
      ustage[e * 32 + kk] = (kk < 10) ? f2b(src[kk]) : (u16)0;
    }
  }
  __syncthreads();  // EAs ready

  // ---- MFMA-P: P = EA @ eaeT -> ebuf ----
  {
    bf16x8 aEA[2];
#pragma unroll
    for (int mt = 0; mt < 2; ++mt)
      aEA[mt] = *(const bf16x8*)(ustage + (wrow + mt * 16 + cl_) * 32 + ko);
    bf16x8 b[8];
#pragma unroll
    for (int nt = 0; nt < 8; ++nt)
      b[nt] = *(const bf16x8*)(WT_eae + (nt * 16 + cl_) * 32 + ko);
#pragma unroll
    for (int mt = 0; mt < 2; ++mt)
#pragma unroll
      for (int nt = 0; nt < 8; ++nt) {
        f32x4 pa = {0.f, 0.f, 0.f, 0.f};
        pa = __builtin_amdgcn_mfma_f32_16x16x32_bf16(aEA[mt], b[nt], pa, 0, 0, 0);
#pragma unroll
        for (int r = 0; r < 4; ++r) {
          int row = wrow + mt * 16 + g4 * 4 + r;
          int col = nt * 16 + cl_;
          ebuf[row * 128 + (col ^ ((row & 7) * 8))] = f2b(pa[r]);
        }
      }
  }
  __syncthreads();  // P visible

  // ---- att scalar (VALU): sigmoid(relu(h1+h2+P).w2 + b2) ----
  {
    float s = 0.f;
    for (int jb = jb0; jb < jb0 + 64; jb += 8) {
      u16x8 h1 = *(const u16x8*)(T1 + (long)rn * 256 + jb);
      u16x8 h2 = *(const u16x8*)(T2 + (long)cn * 256 + jb);
      u16x8 pp = *(const u16x8*)(ebuf + e * 128 + (jb ^ ((e & 7) * 8)));
#pragma unroll
      for (int i = 0; i < 8; ++i)
        s += fmaxf(b2f(h1[i]) + b2f(h2[i]) + b2f(pp[i]), 0.f) * ea_w2[jb + i];
    }
    attP[half * 128 + e] = s;
  }
  __syncthreads();  // attP done; ebuf free

  if (t < 128) attS[t] = 1.f / (1.f + __expf(-(attP[t] + attP[128 + t] + ea_b2[0])));

  // ---- MFMA-U: U = relu(EA @ ee1T + b1) -> ebuf ----
  {
    bf16x8 aEA[2];
#pragma unroll
    for (int mt = 0; mt < 2; ++mt)
      aEA[mt] = *(const bf16x8*)(ustage + (wrow + mt * 16 + cl_) * 32 + ko);
    bf16x8 b[8];
#pragma unroll
    for (int nt = 0; nt < 8; ++nt)
      b[nt] = *(const bf16x8*)(WT_ee1 + (nt * 16 + cl_) * 32 + ko);
#pragma unroll
    for (int mt = 0; mt < 2; ++mt)
#pragma unroll
      for (int nt = 0; nt < 8; ++nt) {
        float bb = ee_b1[nt * 16 + cl_];
        f32x4 ua;
        ua[0] = bb; ua[1] = bb; ua[2] = bb; ua[3] = bb;
        ua = __builtin_amdgcn_mfma_f32_16x16x32_bf16(aEA[mt], b[nt], ua, 0, 0, 0);
#pragma unroll
        for (int r = 0; r < 4; ++r) {
          int row = wrow + mt * 16 + g4 * 4 + r;
          int col = nt * 16 + cl_;
          ebuf[row * 128 + (col ^ ((row & 7) * 8))] = f2b(fmaxf(ua[r], 0.f));
        }
      }
  }
  __syncthreads();  // attS visible to all (U is wave-local)

  // ---- eeL2: F = U @ ee_w2 + b2 ; w_ef = att*F -> ebuf (nt-halved, A hoisted) ----
  {
    bf16x8 a2[4][2];
#pragma unroll
    for (int c = 0; c < 4; ++c)
#pragma unroll
      for (int mt = 0; mt < 2; ++mt) {
        int row = wrow + mt * 16 + cl_;
        a2[c][mt] = *(const bf16x8*)(ebuf + row * 128 + ((c * 32 + ko) ^ ((row & 7) * 8)));
      }
#pragma unroll
    for (int hh = 0; hh < 2; ++hh) {
      f32x4 acc[2][4];
#pragma unroll
      for (int n4 = 0; n4 < 4; ++n4) {
        float bb = ee_b2[(hh * 4 + n4) * 16 + cl_];
#pragma unroll
        for (int mt = 0; mt < 2; ++mt) { acc[mt][n4][0] = bb; acc[mt][n4][1] = bb; acc[mt][n4][2] = bb; acc[mt][n4][3] = bb; }
      }
#pragma unroll
      for (int c = 0; c < 4; ++c)
#pragma unroll
        for (int n4 = 0; n4 < 4; ++n4) {
          bf16x8 b = *(const bf16x8*)(WT_ee2 + ((hh * 4 + n4) * 16 + cl_) * 128 + c * 32 + ko);
#pragma unroll
          for (int mt = 0; mt < 2; ++mt)
            acc[mt][n4] = __builtin_amdgcn_mfma_f32_16x16x32_bf16(a2[c][mt], b, acc[mt][n4], 0, 0, 0);
        }
#pragma unroll
      for (int mt = 0; mt < 2; ++mt)
#pragma unroll
        for (int r = 0; r < 4; ++r) {
          int row = wrow + mt * 16 + g4 * 4 + r;
          float av = attS[row];
#pragma unroll
          for (int n4 = 0; n4 < 4; ++n4) {
            int col = (hh * 4 + n4) * 16 + cl_;
            ebuf[row * 128 + (col ^ ((row & 7) * 8))] = f2b(av * acc[mt][n4][r]);
          }
        }
    }
  }

  // ---- G: g = w_ef @ Wab ; z1 = relu(cn1[rn]+cn2[cn] + g) -> ebuf (nt-halved) ----
  {
    bf16x8 a2[4][2];
#pragma unroll
    for (int c = 0; c < 4; ++c)
#pragma unroll
      for (int mt = 0; mt < 2; ++mt) {
        int row = wrow + mt * 16 + cl_;
        a2[c][mt] = *(const bf16x8*)(ebuf + row * 128 + ((c * 32 + ko) ^ ((row & 7) * 8)));
      }
#pragma unroll
    for (int hh = 0; hh < 2; ++hh) {
      f32x4 acc[2][4];
#pragma unroll
      for (int n4 = 0; n4 < 4; ++n4)
#pragma unroll
        for (int mt = 0; mt < 2; ++mt) { acc[mt][n4][0] = 0.f; acc[mt][n4][1] = 0.f; acc[mt][n4][2] = 0.f; acc[mt][n4][3] = 0.f; }
#pragma unroll
      for (int c = 0; c < 4; ++c)
#pragma unroll
        for (int n4 = 0; n4 < 4; ++n4) {
          bf16x8 b = *(const bf16x8*)(WT_ab + ((hh * 4 + n4) * 16 + cl_) * 128 + c * 32 + ko);
#pragma unroll
          for (int mt = 0; mt < 2; ++mt)
            acc[mt][n4] = __builtin_amdgcn_mfma_f32_16x16x32_bf16(a2[c][mt], b, acc[mt][n4], 0, 0, 0);
        }
      u16x8 v1[4], v2[4];
#pragma unroll
      for (int k = 0; k < 4; ++k) {
        v1[k] = *(const u16x8*)(T1 + (long)rs * 256 + 128 + hh * 64 + cq + k * 8);
        v2[k] = *(const u16x8*)(T2 + (long)cs * 256 + 128 + hh * 64 + cq + k * 8);
      }
#pragma unroll
      for (int k = 0; k < 4; ++k) {
        u16x8 p;
#pragma unroll
        for (int i = 0; i < 8; ++i) p[i] = f2b(b2f(v1[k][i]) + b2f(v2[k][i]));
        *(u16x8*)(cstage + (srow & 31) * 64 + ((cq + k * 8) ^ ((srow & 7) * 8))) = p;
      }
#pragma unroll
      for (int mt = 0; mt < 2; ++mt)
#pragma unroll
        for (int r = 0; r < 4; ++r) {
          int row = wrow + mt * 16 + g4 * 4 + r;
#pragma unroll
          for (int n4 = 0; n4 < 4; ++n4) {
            int col = (hh * 4 + n4) * 16 + cl_;
            int cc = col - hh * 64;
            float v = acc[mt][n4][r] + b2f(cstage[(row & 31) * 64 + (cc ^ ((row & 7) * 8))]);
            ebuf[row * 128 + (col ^ ((row & 7) * 8))] = f2b(fmaxf(v, 0.f));
          }
        }
    }
  }

  // ---- clL2: z2 = relu(z1 @ cl_w2 + b2) (N=64) ----
  f32x4 acc2[2][4];
#pragma unroll
  for (int nt = 0; nt < 4; ++nt) {
    float bb = cl_b2[nt * 16 + cl_];
#pragma unroll
    for (int mt = 0; mt < 2; ++mt) { acc2[mt][nt][0] = bb; acc2[mt][nt][1] = bb; acc2[mt][nt][2] = bb; acc2[mt][nt][3] = bb; }
  }
#pragma unroll
  for (int c = 0; c < 4; ++c) {
    bf16x8 a[2], b[4];
#pragma unroll
    for (int mt = 0; mt < 2; ++mt) {
      int row = wrow + mt * 16 + cl_;
      a[mt] = *(const bf16x8*)(ebuf + row * 128 + ((c * 32 + ko) ^ ((row & 7) * 8)));
    }
#pragma unroll
    for (int nt = 0; nt < 4; ++nt)
      b[nt] = *(const bf16x8*)(WT_cl2 + (nt * 16 + cl_) * 128 + c * 32 + ko);
#pragma unroll
    for (int mt = 0; mt < 2; ++mt)
#pragma unroll
      for (int nt = 0; nt < 4; ++nt)
        acc2[mt][nt] = __builtin_amdgcn_mfma_f32_16x16x32_bf16(a[mt], b[nt], acc2[mt][nt], 0, 0, 0);
  }
#pragma unroll
  for (int mt = 0; mt < 2; ++mt)
#pragma unroll
    for (int r = 0; r < 4; ++r) {
      int row = wrow + mt * 16 + g4 * 4 + r;
#pragma unroll
      for (int nt = 0; nt < 4; ++nt) {
        int col = nt * 16 + cl_;
        ebuf[row * 128 + (col ^ ((row & 7) * 8))] = f2b(fmaxf(acc2[mt][nt][r], 0.f));
      }
    }
  __syncthreads();

  // ---- clL3: scatter to original edge order via eid ----
  if (t < 128) {
    long ge = eid[ebase + t];
    float o0 = cl_b3[0], o1 = cl_b3[1];
    for (int k8 = 0; k8 < 64; k8 += 8) {
      u16x8 v = *(const u16x8*)(ebuf + t * 128 + (k8 ^ ((t & 7) * 8)));
#pragma unroll
      for (int i = 0; i < 8; ++i) {
        float z = b2f(v[i]);
        o0 += z * cl_w3[(k8 + i) * 2];
        o1 += z * cl_w3[(k8 + i) * 2 + 1];
      }
    }
    *(float2*)(out + ge * 2) = make_float2(o0, o1);
  }
}

extern "C" void kernel_launch(void* const* d_in, const int* in_sizes, int n_in,
                              void* d_out, int out_size, void* d_ws, size_t ws_size,
                              hipStream_t stream) {
  (void)in_sizes; (void)n_in; (void)out_size; (void)ws_size;
  const float* x = (const float*)d_in[0];
  const int* ei = (const int*)d_in[1];
  const float* eattr = (const float*)d_in[2];
  const float* ne_w1 = (const float*)d_in[3];
  const float* ne_b1 = (const float*)d_in[4];
  const float* ne_w2 = (const float*)d_in[5];
  const float* ne_b2 = (const float*)d_in[6];
  const float* ee_w1 = (const float*)d_in[7];
  const float* ee_b1 = (const float*)d_in[8];
  const float* ee_w2 = (const float*)d_in[9];
  const float* ee_b2 = (const float*)d_in[10];
  const float* ea_w1 = (const float*)d_in[11];
  const float* ea_b1 = (const float*)d_in[12];
  const float* ea_w2 = (const float*)d_in[13];
  const float* ea_b2 = (const float*)d_in[14];
  const float* gcn_w = (const float*)d_in[15];
  const float* gcn_b = (const float*)d_in[16];
  const float* bn_g = (const float*)d_in[17];
  const float* bn_b = (const float*)d_in[18];
  const float* skip_w = (const float*)d_in[19];
  const float* skip_b = (const float*)d_in[20];
  const float* cl_w1 = (const float*)d_in[21];
  const float* cl_b1 = (const float*)d_in[22];
  const float* cl_w2 = (const float*)d_in[23];
  const float* cl_b2 = (const float*)d_in[24];
  const float* cl_w3 = (const float*)d_in[25];
  const float* cl_b3 = (const float*)d_in[26];
  float* out = (float*)d_out;

  // ws layout (bytes); WP grew to 217088 elems (434176 B) -> subsequent ptrs shifted
  char* ws = (char*)d_ws;
  u16* hb0 = (u16*)ws;                              // 12.8e6
  u16* hb1 = (u16*)(ws + 12800000);                 // 12.8e6
  float* A = (float*)(ws + 25600000);               // 25.6e6 f32 (skip out) / T1 overlay
  u16* mn = (u16*)(ws + 51200000);                  // 12.8e6 bf16 scaled message
  float* agg = (float*)(ws + 64000000);             // 25.6e6 / T2 overlay
  unsigned* deg = (unsigned*)(ws + 89600000);       // 200e3
  float* dinv = (float*)(ws + 89800000);            // 200e3
  double* sums = (double*)(ws + 90000000);          // 2048
  u16* WP = (u16*)(ws + 90002048);                  // 434176 B -> ends 90436224
  int* offs = (int*)(ws + 90436224);                // 200e3
  int* cursor = (int*)(ws + 90636224);              // 200e3
  int* bsum = (int*)(ws + 90836224);                // 1024
  int* boff = (int*)(ws + 90837248);                // 1024
  int* elr = (int*)(ws + 90838272);                 // 3.2e6
  int* ecn = (int*)(ws + 94038272);                 // 3.2e6
  int* eid = (int*)(ws + 97238272);                 // 3.2e6 (end ~100.44 MB)
  u16* T1 = (u16*)A;
  u16* T2 = (u16*)agg;

  u16* WP_ne2 = WP;
  u16* WP_gcn = WP + 16384;
  u16* WP_skip = WP + 65536;
  u16* WP_t4 = WP + 98304;
  u16* WP_ab = WP + 163840;
  u16* WP_ee2 = WP + 180224;
  u16* WP_cl2 = WP + 196608;
  u16* WP_ee1 = WP + 204800;
  u16* WP_eae = WP + 208896;
  u16* WP_ne1 = WP + 212992;

  const int* col = ei + NE;
  const int NGB = (NN + 255) / 256;    // 196 (scan kernels)
  const int NGB128 = (NN + 127) / 128; // 391 (BM=128 GEMMs)

  k_prep<<<848, 256, 0, stream>>>(ea_w1, cl_w1, ee_w2, cl_w2, gcn_w, skip_w, ne_w2, ee_w1, ne_w1, WP);
  hipMemsetAsync(deg, 0, NN * sizeof(unsigned), stream);
  k_deg<<<(NE + 255) / 256, 256, 0, stream>>>(col, deg);
  k_scan1<<<NGB, 256, 0, stream>>>(deg, bsum);
  k_scan2<<<1, 256, 0, stream>>>(bsum, boff, NGB);
  k_scan3<<<NGB, 256, 0, stream>>>(deg, boff, offs, cursor, dinv);
  k_fill<<<(NE + 255) / 256, 256, 0, stream>>>(ei, cursor, elr, ecn, eid);

  k_nodeenc<<<NGB128, 256, 0, stream>>>(x, WP_ne1, WP_ne2, ne_b1, ne_b2, hb0);

  u16* hin = hb0; u16* hout = hb1;
  for (int i = 0; i < 3; ++i) {
    k_gcnskip<<<NGB128, 256, 0, stream>>>(hin, WP_gcn + (long)i * 16384,
                                          (i > 0) ? (WP_skip + (long)(i - 1) * 16384) : nullptr,
                                          dinv, mn, A);
    hipMemsetAsync(sums, 0, 256 * sizeof(double), stream);
    k_agg<<<(NN + 63) / 64, 256, 0, stream>>>(offs, deg, elr, dinv, mn, gcn_b + i * H, agg, sums);
    if (i > 0)
      k_bnskip<true><<<NN * H / 256, 256, 0, stream>>>(
          agg, sums, bn_g + i * H, bn_b + i * H, A, skip_b + (i - 1) * H, hout);
    else
      k_bnskip<false><<<NN * H / 256, 256, 0, stream>>>(
          agg, sums, bn_g, bn_b, nullptr, nullptr, hout);
    u16* tmp = hin; hin = hout; hout = tmp;
  }

  k_ntab<<<NGB128, 256, 0, stream>>>(hin, WP_t4, ea_b1, cl_b1, T1, T2);

  k_edge<<<NE / EPB, 256, 0, stream>>>(
      elr, ecn, eid, eattr, T1, T2, ee_b1, ee_b2, ea_w2, ea_b2,
      WP_ee1, WP_eae, WP_ee2, WP_ab, WP_cl2, cl_b2, cl_w3, cl_b3, out);
}

// Round 11
// 846.566 us; speedup vs baseline: 1.0715x; 1.0445x over previous
//
#include <hip/hip_runtime.h>
#include <math.h>

#define NN 50000
#define NE 800000
#define H 128

typedef short bf16x8 __attribute__((ext_vector_type(8)));
typedef unsigned short u16x8 __attribute__((ext_vector_type(8)));
typedef float f32x4 __attribute__((ext_vector_type(4)));
typedef unsigned short u16;

__device__ inline u16 f2b(float f) {
  unsigned u = __float_as_uint(f);
  return (u16)((u + 0x7FFF + ((u >> 16) & 1)) >> 16);
}
__device__ inline float b2f(u16 s) { return __uint_as_float(((unsigned)s) << 16); }

// =============== weight prep: bf16, transposed WT[n][k] = W[k][n] ===============
// WP element offsets:
//   ne2:0 gcn:16384(x3) skip:65536(x2)
//   t4:98304 (hn1,cn1,hn2,cn2 each 16384)
//   ab:163840 ee2:180224 cl2:196608(8192) ee1:204800([128][32]) eae:208896([128][32])
//   ne1:212992([128][32]) end:217088
__global__ void k_prep(const float* __restrict__ ea_w1, const float* __restrict__ cl_w1,
                       const float* __restrict__ ee_w2, const float* __restrict__ cl_w2,
                       const float* __restrict__ gcn_w, const float* __restrict__ skip_w,
                       const float* __restrict__ ne_w2, const float* __restrict__ ee_w1,
                       const float* __restrict__ ne_w1, u16* __restrict__ WP) {
  int idx = blockIdx.x * 256 + threadIdx.x;
  if (idx >= 217088) return;
  float v;
  if (idx < 16384) {            // ne2
    int n = idx >> 7, k = idx & 127;
    v = ne_w2[k * 128 + n];
  } else if (idx < 65536) {     // gcn
    int lo = idx - 16384; int i = lo >> 14; int n = (lo >> 7) & 127, k = lo & 127;
    v = gcn_w[i * 16384 + k * 128 + n];
  } else if (idx < 98304) {     // skip
    int lo = idx - 65536; int i = lo >> 14; int n = (lo >> 7) & 127, k = lo & 127;
    v = skip_w[i * 16384 + k * 128 + n];
  } else if (idx < 163840) {    // t4: hn1, cn1, hn2, cn2
    int lo = idx - 98304; int tab = lo >> 14; int n = (lo >> 7) & 127, k = lo & 127;
    if (tab == 0) v = ea_w1[k * 128 + n];
    else if (tab == 1) v = cl_w1[k * 128 + n];
    else if (tab == 2) v = ea_w1[(128 + k) * 128 + n];
    else v = cl_w1[(128 + k) * 128 + n];
  } else if (idx < 180224) {    // ab
    int lo = idx - 163840; int n = lo >> 7, k = lo & 127;
    v = cl_w1[k * 128 + n] + cl_w1[(128 + k) * 128 + n];
  } else if (idx < 196608) {    // ee2
    int lo = idx - 180224; int n = lo >> 7, k = lo & 127;
    v = ee_w2[k * 128 + n];
  } else if (idx < 204800) {    // cl2 [64][128]
    int lo = idx - 196608; int n = lo >> 7, k = lo & 127;
    v = cl_w2[k * 64 + n];
  } else if (idx < 208896) {    // ee1 [128][32] zero-padded K
    int lo = idx - 204800; int n = lo >> 5, k = lo & 31;
    v = (k < 10) ? ee_w1[k * 128 + n] : 0.f;
  } else if (idx < 212992) {    // eae [128][32] zero-padded K (ea_w1 rows 256..265)
    int lo = idx - 208896; int n = lo >> 5, k = lo & 31;
    v = (k < 10) ? ea_w1[(256 + k) * 128 + n] : 0.f;
  } else {                      // ne1 [128][32] zero-padded K
    int lo = idx - 212992; int n = lo >> 5, k = lo & 31;
    v = (k < 10) ? ne_w1[k * 128 + n] : 0.f;
  }
  WP[idx] = f2b(v);
}

// =============== fused node encoder: hb0 = relu(x@ne_w1+b1) @ ne_w2 + b2 ===============
__global__ __launch_bounds__(256, 2) void k_nodeenc(
    const float* __restrict__ x, const u16* __restrict__ WT1,
    const u16* __restrict__ WT2, const float* __restrict__ b1,
    const float* __restrict__ b2, u16* __restrict__ outB) {
  __shared__ u16 XL[128 * 32];
  __shared__ u16 As[128 * 128];
  int t = threadIdx.x;
  long base = (long)blockIdx.x * 128;
  for (int idx = t; idx < 128 * 32; idx += 256) {
    int row = idx >> 5, kk = idx & 31;
    long gr = base + row; if (gr >= NN) gr = 0;
    XL[idx] = (kk < 10) ? f2b(x[gr * 10 + kk]) : (u16)0;
  }
  __syncthreads();
  int l = t & 63, w = t >> 6;
  int wrow = w * 32;
  int cl_ = l & 15, g4 = l >> 4, ko = g4 * 8;
  // L1
  {
    bf16x8 a[2], b[8];
#pragma unroll
    for (int mt = 0; mt < 2; ++mt)
      a[mt] = *(const bf16x8*)(XL + (wrow + mt * 16 + cl_) * 32 + ko);
#pragma unroll
    for (int nt = 0; nt < 8; ++nt)
      b[nt] = *(const bf16x8*)(WT1 + (nt * 16 + cl_) * 32 + ko);
#pragma unroll
    for (int mt = 0; mt < 2; ++mt)
#pragma unroll
      for (int nt = 0; nt < 8; ++nt) {
        float bb = b1[nt * 16 + cl_];
        f32x4 ua;
        ua[0] = bb; ua[1] = bb; ua[2] = bb; ua[3] = bb;
        ua = __builtin_amdgcn_mfma_f32_16x16x32_bf16(a[mt], b[nt], ua, 0, 0, 0);
#pragma unroll
        for (int r = 0; r < 4; ++r) {
          int row = wrow + mt * 16 + g4 * 4 + r;
          int col = nt * 16 + cl_;
          As[row * 128 + (col ^ ((row & 7) * 8))] = f2b(fmaxf(ua[r], 0.f));
        }
      }
  }
  // L2 (wave-local As rows)
  f32x4 acc[2][8];
#pragma unroll
  for (int nt = 0; nt < 8; ++nt) {
    float bb = b2[nt * 16 + cl_];
#pragma unroll
    for (int mt = 0; mt < 2; ++mt) { acc[mt][nt][0] = bb; acc[mt][nt][1] = bb; acc[mt][nt][2] = bb; acc[mt][nt][3] = bb; }
  }
#pragma unroll
  for (int c = 0; c < 4; ++c) {
    bf16x8 a[2], b[8];
#pragma unroll
    for (int mt = 0; mt < 2; ++mt) {
      int row = wrow + mt * 16 + cl_;
      a[mt] = *(const bf16x8*)(As + row * 128 + ((c * 32 + ko) ^ ((row & 7) * 8)));
    }
#pragma unroll
    for (int nt = 0; nt < 8; ++nt)
      b[nt] = *(const bf16x8*)(WT2 + (nt * 16 + cl_) * 128 + c * 32 + ko);
#pragma unroll
    for (int mt = 0; mt < 2; ++mt)
#pragma unroll
      for (int nt = 0; nt < 8; ++nt)
        acc[mt][nt] = __builtin_amdgcn_mfma_f32_16x16x32_bf16(a[mt], b[nt], acc[mt][nt], 0, 0, 0);
  }
#pragma unroll
  for (int mt = 0; mt < 2; ++mt)
#pragma unroll
    for (int r = 0; r < 4; ++r) {
      long row = base + wrow + mt * 16 + g4 * 4 + r;
      if (row >= NN) continue;
#pragma unroll
      for (int nt = 0; nt < 8; ++nt)
        outB[row * 128 + nt * 16 + cl_] = f2b(acc[mt][nt][r]);
    }
}

// =============== gcn(+skip) GEMM with fused BN staging ===============
// MODE 0: stage bf16 hb directly (layer 0, input = node-encoder output).
// MODE 1: stage relu(BN(agg)) — consumes the PREVIOUS layer's agg/sums (k_bnskip killed).
// MODE 2: stage relu(BN(agg)) + AfIn + skipb.
// Aliasing safe: stage reads only this block's rows of agg/AfIn BEFORE the barrier;
// pass-2 writes the same rows AFTER — no cross-block row sharing.
template <int MODE>
__global__ __launch_bounds__(256, 2) void k_gcnskip(
    const u16* __restrict__ hbin,
    const float* __restrict__ agg, const double* __restrict__ sums,
    const float* __restrict__ g, const float* __restrict__ b,
    const float* __restrict__ AfIn, const float* __restrict__ skipb,
    const u16* __restrict__ WTg, const u16* __restrict__ WTs,
    const float* __restrict__ dinv, u16* __restrict__ mn, float* __restrict__ Af) {
  __shared__ u16 As[128 * 128];
  __shared__ float sc_[128], sh_[128];
  int t = threadIdx.x;
  long base = (long)blockIdx.x * 128;
  if (MODE > 0) {
    if (t < 128) {
      double mu = sums[t] * (1.0 / NN);
      double var = sums[128 + t] * (1.0 / NN) - mu * mu;
      float inv = (float)(1.0 / sqrt(var + 1e-5));
      float sc = inv * g[t];
      sc_[t] = sc;
      sh_[t] = b[t] - (float)mu * sc;
    }
    __syncthreads();
    for (int idx = t; idx < 128 * 16; idx += 256) {
      int row = idx >> 4, k8 = (idx & 15) * 8;
      long gr = base + row; if (gr >= NN) gr = 0;
      float4 a0 = *(const float4*)(agg + gr * 128 + k8);
      float4 a1 = *(const float4*)(agg + gr * 128 + k8 + 4);
      float v[8] = {a0.x, a0.y, a0.z, a0.w, a1.x, a1.y, a1.z, a1.w};
      float f[8] = {0, 0, 0, 0, 0, 0, 0, 0};
      if (MODE == 2) {
        float4 f0 = *(const float4*)(AfIn + gr * 128 + k8);
        float4 f1 = *(const float4*)(AfIn + gr * 128 + k8 + 4);
        f[0] = f0.x; f[1] = f0.y; f[2] = f0.z; f[3] = f0.w;
        f[4] = f1.x; f[5] = f1.y; f[6] = f1.z; f[7] = f1.w;
      }
      u16x8 p;
#pragma unroll
      for (int k = 0; k < 8; ++k) {
        int j = k8 + k;
        float val = fmaxf(v[k] * sc_[j] + sh_[j], 0.f);
        if (MODE == 2) val += f[k] + skipb[j];
        p[k] = f2b(val);
      }
      *(u16x8*)(As + row * 128 + (k8 ^ ((row & 7) * 8))) = p;
    }
  } else {
    for (int idx = t; idx < 128 * 16; idx += 256) {
      int row = idx >> 4, k8 = (idx & 15) * 8;
      long gr = base + row; if (gr >= NN) gr = 0;
      uint4 v = *(const uint4*)(hbin + gr * 128 + k8);
      *(uint4*)(As + row * 128 + (k8 ^ ((row & 7) * 8))) = v;
    }
  }
  __syncthreads();
  int l = t & 63, w = t >> 6;
  int wrow = w * 32;
  int cl_ = l & 15, g4 = l >> 4, ko = g4 * 8;
  // pass 1: gcn -> mn (dinv-premultiplied bf16)
  {
    f32x4 acc[2][8];
#pragma unroll
    for (int nt = 0; nt < 8; ++nt)
#pragma unroll
      for (int mt = 0; mt < 2; ++mt) { acc[mt][nt][0] = 0.f; acc[mt][nt][1] = 0.f; acc[mt][nt][2] = 0.f; acc[mt][nt][3] = 0.f; }
#pragma unroll
    for (int c = 0; c < 4; ++c) {
      bf16x8 a[2], b8[8];
#pragma unroll
      for (int mt = 0; mt < 2; ++mt) {
        int row = wrow + mt * 16 + cl_;
        a[mt] = *(const bf16x8*)(As + row * 128 + ((c * 32 + ko) ^ ((row & 7) * 8)));
      }
#pragma unroll
      for (int nt = 0; nt < 8; ++nt)
        b8[nt] = *(const bf16x8*)(WTg + (nt * 16 + cl_) * 128 + c * 32 + ko);
#pragma unroll
      for (int mt = 0; mt < 2; ++mt)
#pragma unroll
        for (int nt = 0; nt < 8; ++nt)
          acc[mt][nt] = __builtin_amdgcn_mfma_f32_16x16x32_bf16(a[mt], b8[nt], acc[mt][nt], 0, 0, 0);
    }
#pragma unroll
    for (int mt = 0; mt < 2; ++mt)
#pragma unroll
      for (int r = 0; r < 4; ++r) {
        long row = base + wrow + mt * 16 + g4 * 4 + r;
        if (row >= NN) continue;
        float dv = dinv[row];
#pragma unroll
        for (int nt = 0; nt < 8; ++nt)
          mn[row * 128 + nt * 16 + cl_] = f2b(dv * acc[mt][nt][r]);
      }
  }
  // pass 2: skip -> Af (f32); As read-only, no barrier needed
  if (WTs) {
    f32x4 acc[2][8];
#pragma unroll
    for (int nt = 0; nt < 8; ++nt)
#pragma unroll
      for (int mt = 0; mt < 2; ++mt) { acc[mt][nt][0] = 0.f; acc[mt][nt][1] = 0.f; acc[mt][nt][2] = 0.f; acc[mt][nt][3] = 0.f; }
#pragma unroll
    for (int c = 0; c < 4; ++c) {
      bf16x8 a[2], b8[8];
#pragma unroll
      for (int mt = 0; mt < 2; ++mt) {
        int row = wrow + mt * 16 + cl_;
        a[mt] = *(const bf16x8*)(As + row * 128 + ((c * 32 + ko) ^ ((row & 7) * 8)));
      }
#pragma unroll
      for (int nt = 0; nt < 8; ++nt)
        b8[nt] = *(const bf16x8*)(WTs + (nt * 16 + cl_) * 128 + c * 32 + ko);
#pragma unroll
      for (int mt = 0; mt < 2; ++mt)
#pragma unroll
        for (int nt = 0; nt < 8; ++nt)
          acc[mt][nt] = __builtin_amdgcn_mfma_f32_16x16x32_bf16(a[mt], b8[nt], acc[mt][nt], 0, 0, 0);
    }
#pragma unroll
    for (int mt = 0; mt < 2; ++mt)
#pragma unroll
      for (int r = 0; r < 4; ++r) {
        long row = base + wrow + mt * 16 + g4 * 4 + r;
        if (row >= NN) continue;
#pragma unroll
        for (int nt = 0; nt < 8; ++nt)
          Af[row * 128 + nt * 16 + cl_] = acc[mt][nt][r];
      }
  }
}

// =============== 4-table GEMM with fused BN+skip staging (h3) ===============
// Stages relu(BN(agg)) + AfIn + skipb; writes T1 (= A region) and T2 (= agg region).
// Aliasing safe per-block (reads own rows before barrier, writes own rows after).
__global__ __launch_bounds__(256, 2) void k_ntab(
    const float* __restrict__ agg, const double* __restrict__ sums,
    const float* __restrict__ g, const float* __restrict__ b,
    const float* __restrict__ AfIn, const float* __restrict__ skipb,
    const u16* __restrict__ WPt4,
    const float* __restrict__ ea_b1, const float* __restrict__ cl_b1,
    u16* __restrict__ T1, u16* __restrict__ T2) {
  __shared__ u16 As[128 * 128];
  __shared__ float sc_[128], sh_[128];
  int t = threadIdx.x;
  long base = (long)blockIdx.x * 128;
  if (t < 128) {
    double mu = sums[t] * (1.0 / NN);
    double var = sums[128 + t] * (1.0 / NN) - mu * mu;
    float inv = (float)(1.0 / sqrt(var + 1e-5));
    float sc = inv * g[t];
    sc_[t] = sc;
    sh_[t] = b[t] - (float)mu * sc;
  }
  __syncthreads();
  for (int idx = t; idx < 128 * 16; idx += 256) {
    int row = idx >> 4, k8 = (idx & 15) * 8;
    long gr = base + row; if (gr >= NN) gr = 0;
    float4 a0 = *(const float4*)(agg + gr * 128 + k8);
    float4 a1 = *(const float4*)(agg + gr * 128 + k8 + 4);
    float4 f0 = *(const float4*)(AfIn + gr * 128 + k8);
    float4 f1 = *(const float4*)(AfIn + gr * 128 + k8 + 4);
    float v[8] = {a0.x, a0.y, a0.z, a0.w, a1.x, a1.y, a1.z, a1.w};
    float f[8] = {f0.x, f0.y, f0.z, f0.w, f1.x, f1.y, f1.z, f1.w};
    u16x8 p;
#pragma unroll
    for (int k = 0; k < 8; ++k) {
      int j = k8 + k;
      float val = fmaxf(v[k] * sc_[j] + sh_[j], 0.f) + f[k] + skipb[j];
      p[k] = f2b(val);
    }
    *(u16x8*)(As + row * 128 + (k8 ^ ((row & 7) * 8))) = p;
  }
  __syncthreads();
  int l = t & 63, w = t >> 6;
  int wrow = w * 32;
  int cl_ = l & 15, g4 = l >> 4, ko = g4 * 8;
  for (int y = 0; y < 4; ++y) {
    const u16* WT = WPt4 + y * 16384;
    const float* bias = (y == 0) ? ea_b1 : ((y == 1) ? cl_b1 : nullptr);
    u16* outT = (y < 2) ? T1 : T2;
    int colOff = (y & 1) * 128;
    f32x4 acc[2][8];
#pragma unroll
    for (int nt = 0; nt < 8; ++nt) {
      float bb = bias ? bias[nt * 16 + cl_] : 0.f;
#pragma unroll
      for (int mt = 0; mt < 2; ++mt) { acc[mt][nt][0] = bb; acc[mt][nt][1] = bb; acc[mt][nt][2] = bb; acc[mt][nt][3] = bb; }
    }
#pragma unroll
    for (int c = 0; c < 4; ++c) {
      bf16x8 a[2], b8[8];
#pragma unroll
      for (int mt = 0; mt < 2; ++mt) {
        int row = wrow + mt * 16 + cl_;
        a[mt] = *(const bf16x8*)(As + row * 128 + ((c * 32 + ko) ^ ((row & 7) * 8)));
      }
#pragma unroll
      for (int nt = 0; nt < 8; ++nt)
        b8[nt] = *(const bf16x8*)(WT + (nt * 16 + cl_) * 128 + c * 32 + ko);
#pragma unroll
      for (int mt = 0; mt < 2; ++mt)
#pragma unroll
        for (int nt = 0; nt < 8; ++nt)
          acc[mt][nt] = __builtin_amdgcn_mfma_f32_16x16x32_bf16(a[mt], b8[nt], acc[mt][nt], 0, 0, 0);
    }
#pragma unroll
    for (int mt = 0; mt < 2; ++mt)
#pragma unroll
      for (int r = 0; r < 4; ++r) {
        long row = base + wrow + mt * 16 + g4 * 4 + r;
        if (row >= NN) continue;
#pragma unroll
        for (int nt = 0; nt < 8; ++nt)
          outT[row * 256 + colOff + nt * 16 + cl_] = f2b(acc[mt][nt][r]);
      }
  }
}

// =============== degree ===============
__global__ void k_deg(const int* __restrict__ col, unsigned* __restrict__ deg) {
  int e = blockIdx.x * 256 + threadIdx.x;
  if (e < NE) atomicAdd(&deg[col[e]], 1u);
}

// =============== CSR build ===============
__global__ __launch_bounds__(256) void k_scan1(const unsigned* __restrict__ deg,
                                               int* __restrict__ bsum) {
  __shared__ int s[256];
  int t = threadIdx.x, v = blockIdx.x * 256 + t;
  s[t] = (v < NN) ? (int)deg[v] : 0;
  __syncthreads();
  for (int off = 128; off > 0; off >>= 1) {
    if (t < off) s[t] += s[t + off];
    __syncthreads();
  }
  if (t == 0) bsum[blockIdx.x] = s[0];
}
__global__ __launch_bounds__(256) void k_scan2(const int* __restrict__ bsum,
                                               int* __restrict__ boff, int nb) {
  __shared__ int s[256];
  int t = threadIdx.x;
  int v = (t < nb) ? bsum[t] : 0;
  s[t] = v;
  __syncthreads();
  for (int off = 1; off < 256; off <<= 1) {
    int x = (t >= off) ? s[t - off] : 0;
    __syncthreads();
    s[t] += x;
    __syncthreads();
  }
  if (t < nb) boff[t] = s[t] - v;
}
__global__ __launch_bounds__(256) void k_scan3(const unsigned* __restrict__ deg,
                                               const int* __restrict__ boff,
                                               int* __restrict__ offs, int* __restrict__ cursor,
                                               float* __restrict__ dinv) {
  __shared__ int s[256];
  int t = threadIdx.x, v = blockIdx.x * 256 + t;
  int d = (v < NN) ? (int)deg[v] : 0;
  s[t] = d;
  __syncthreads();
  for (int off = 1; off < 256; off <<= 1) {
    int x = (t >= off) ? s[t - off] : 0;
    __syncthreads();
    s[t] += x;
    __syncthreads();
  }
  int excl = s[t] - d + boff[blockIdx.x];
  if (v < NN) {
    offs[v] = excl; cursor[v] = excl;
    dinv[v] = 1.0f / sqrtf((float)(d + 1));
  }
}
__global__ void k_fill(const int* __restrict__ ei, int* __restrict__ cursor,
                       int* __restrict__ elr, int* __restrict__ ecn, int* __restrict__ eid) {
  int e = blockIdx.x * 256 + threadIdx.x;
  if (e < NE) {
    int c = ei[NE + e];
    int pos = atomicAdd(&cursor[c], 1);
    elr[pos] = ei[e];
    ecn[pos] = c;
    eid[pos] = e;
  }
}

// =============== CSR aggregate + fused BN stats ===============
__global__ __launch_bounds__(256) void k_agg(
    const int* __restrict__ offs, const unsigned* __restrict__ deg,
    const int* __restrict__ elr, const float* __restrict__ dinv,
    const u16* __restrict__ mn, const float* __restrict__ gb,
    float* __restrict__ agg, double* __restrict__ sums) {
  __shared__ float s_lds[16][128];
  __shared__ float q_lds[16][128];
  int t = threadIdx.x;
  int slot = t >> 4;
  int j8 = (t & 15) * 8;
  float ps[8], pq[8];
#pragma unroll
  for (int k = 0; k < 8; ++k) { ps[k] = 0.f; pq[k] = 0.f; }
  int vbase = blockIdx.x * 64;
  for (int nn = 0; nn < 4; ++nn) {
    int v = vbase + nn * 16 + slot;
    if (v < NN) {
      float acc[8];
      u16x8 m0 = *(const u16x8*)(mn + (long)v * 128 + j8);
#pragma unroll
      for (int k = 0; k < 8; ++k) acc[k] = b2f(m0[k]);
      int start = offs[v];
      int cnt = (int)deg[v];
      for (int i = 0; i < cnt; ++i) {
        u16x8 m = *(const u16x8*)(mn + (long)elr[start + i] * 128 + j8);
#pragma unroll
        for (int k = 0; k < 8; ++k) acc[k] += b2f(m[k]);
      }
      float dv = dinv[v];
#pragma unroll
      for (int k = 0; k < 8; ++k) {
        acc[k] = dv * acc[k] + gb[j8 + k];
        ps[k] += acc[k];
        pq[k] += acc[k] * acc[k];
      }
      *(float4*)(agg + (long)v * 128 + j8) = make_float4(acc[0], acc[1], acc[2], acc[3]);
      *(float4*)(agg + (long)v * 128 + j8 + 4) = make_float4(acc[4], acc[5], acc[6], acc[7]);
    }
  }
#pragma unroll
  for (int k = 0; k < 8; ++k) { s_lds[slot][j8 + k] = ps[k]; q_lds[slot][j8 + k] = pq[k]; }
  __syncthreads();
  if (t < 128) {
    float s = 0.f;
#pragma unroll
    for (int sl = 0; sl < 16; ++sl) s += s_lds[sl][t];
    atomicAdd(&sums[t], (double)s);
  } else {
    int j = t - 128;
    float q = 0.f;
#pragma unroll
    for (int sl = 0; sl < 16; ++sl) q += q_lds[sl][j];
    atomicAdd(&sums[128 + j], (double)q);
  }
}

// =============== fused per-edge head (all GEMMs on MFMA) ===============
// EXACT r8 structure (413 us): CSR-ordered edges (T2-side L2-resident).
#define EPB 128
__global__ __launch_bounds__(256, 2) void k_edge(
    const int* __restrict__ elr, const int* __restrict__ ecn, const int* __restrict__ eid,
    const float* __restrict__ eaf,
    const u16* __restrict__ T1, const u16* __restrict__ T2,
    const float* __restrict__ ee_b1, const float* __restrict__ ee_b2,
    const float* __restrict__ ea_w2, const float* __restrict__ ea_b2,
    const u16* __restrict__ WT_ee1, const u16* __restrict__ WT_eae,
    const u16* __restrict__ WT_ee2, const u16* __restrict__ WT_ab,
    const u16* __restrict__ WT_cl2,
    const float* __restrict__ cl_b2, const float* __restrict__ cl_w3,
    const float* __restrict__ cl_b3,
    float* __restrict__ out) {
  __shared__ u16 ebuf[128 * 128];   // P -> U -> w_ef -> z1 -> z2
  __shared__ u16 ustage[8192];      // EAs[128][32] then 4x per-wave cstage[32][64]
  __shared__ float attP[256];
  __shared__ float attS[128];

  int t = threadIdx.x;
  long ebase = (long)blockIdx.x * EPB;
  int e = t & 127, half = t >> 7;
  int jb0 = half * 64;
  int rn = elr[ebase + e];
  int cn = ecn[ebase + e];

  int l = t & 63, w = t >> 6;
  int wrow = w * 32;
  int cl_ = l & 15, g4 = l >> 4, ko = g4 * 8;

  int srow = wrow + (l >> 1);
  int cq = (l & 1) * 32;
  int rs = elr[ebase + srow];
  int cs = ecn[ebase + srow];
  u16* cstage = ustage + w * 2048;  // wave-local 32x64 slice

  // ---- stage EA (zero-padded K=32), gathered via eid ----
  {
    int k0 = half * 16;
    long ge = eid[ebase + e];
    const float* src = eaf + ge * 10;
#pragma unroll
    for (int k = 0; k < 16; ++k) {
      int kk = k0 + k;
      ustage[e * 32 + kk] = (kk < 10) ? f2b(src[kk]) : (u16)0;
    }
  }
  __syncthreads();  // EAs ready

  // ---- MFMA-P: P = EA @ eaeT -> ebuf ----
  {
    bf16x8 aEA[2];
#pragma unroll
    for (int mt = 0; mt < 2; ++mt)
      aEA[mt] = *(const bf16x8*)(ustage + (wrow + mt * 16 + cl_) * 32 + ko);
    bf16x8 b[8];
#pragma unroll
    for (int nt = 0; nt < 8; ++nt)
      b[nt] = *(const bf16x8*)(WT_eae + (nt * 16 + cl_) * 32 + ko);
#pragma unroll
    for (int mt = 0; mt < 2; ++mt)
#pragma unroll
      for (int nt = 0; nt < 8; ++nt) {
        f32x4 pa = {0.f, 0.f, 0.f, 0.f};
        pa = __builtin_amdgcn_mfma_f32_16x16x32_bf16(aEA[mt], b[nt], pa, 0, 0, 0);
#pragma unroll
        for (int r = 0; r < 4; ++r) {
          int row = wrow + mt * 16 + g4 * 4 + r;
          int col = nt * 16 + cl_;
          ebuf[row * 128 + (col ^ ((row & 7) * 8))] = f2b(pa[r]);
        }
      }
  }
  __syncthreads();  // P visible

  // ---- att scalar (VALU): sigmoid(relu(h1+h2+P).w2 + b2) ----
  {
    float s = 0.f;
    for (int jb = jb0; jb < jb0 + 64; jb += 8) {
      u16x8 h1 = *(const u16x8*)(T1 + (long)rn * 256 + jb);
      u16x8 h2 = *(const u16x8*)(T2 + (long)cn * 256 + jb);
      u16x8 pp = *(const u16x8*)(ebuf + e * 128 + (jb ^ ((e & 7) * 8)));
#pragma unroll
      for (int i = 0; i < 8; ++i)
        s += fmaxf(b2f(h1[i]) + b2f(h2[i]) + b2f(pp[i]), 0.f) * ea_w2[jb + i];
    }
    attP[half * 128 + e] = s;
  }
  __syncthreads();  // attP done; ebuf free

  if (t < 128) attS[t] = 1.f / (1.f + __expf(-(attP[t] + attP[128 + t] + ea_b2[0])));

  // ---- MFMA-U: U = relu(EA @ ee1T + b1) -> ebuf ----
  {
    bf16x8 aEA[2];
#pragma unroll
    for (int mt = 0; mt < 2; ++mt)
      aEA[mt] = *(const bf16x8*)(ustage + (wrow + mt * 16 + cl_) * 32 + ko);
    bf16x8 b[8];
#pragma unroll
    for (int nt = 0; nt < 8; ++nt)
      b[nt] = *(const bf16x8*)(WT_ee1 + (nt * 16 + cl_) * 32 + ko);
#pragma unroll
    for (int mt = 0; mt < 2; ++mt)
#pragma unroll
      for (int nt = 0; nt < 8; ++nt) {
        float bb = ee_b1[nt * 16 + cl_];
        f32x4 ua;
        ua[0] = bb; ua[1] = bb; ua[2] = bb; ua[3] = bb;
        ua = __builtin_amdgcn_mfma_f32_16x16x32_bf16(aEA[mt], b[nt], ua, 0, 0, 0);
#pragma unroll
        for (int r = 0; r < 4; ++r) {
          int row = wrow + mt * 16 + g4 * 4 + r;
          int col = nt * 16 + cl_;
          ebuf[row * 128 + (col ^ ((row & 7) * 8))] = f2b(fmaxf(ua[r], 0.f));
        }
      }
  }
  __syncthreads();  // attS visible to all (U is wave-local)

  // ---- eeL2: F = U @ ee_w2 + b2 ; w_ef = att*F -> ebuf (nt-halved, A hoisted) ----
  {
    bf16x8 a2[4][2];
#pragma unroll
    for (int c = 0; c < 4; ++c)
#pragma unroll
      for (int mt = 0; mt < 2; ++mt) {
        int row = wrow + mt * 16 + cl_;
        a2[c][mt] = *(const bf16x8*)(ebuf + row * 128 + ((c * 32 + ko) ^ ((row & 7) * 8)));
      }
#pragma unroll
    for (int hh = 0; hh < 2; ++hh) {
      f32x4 acc[2][4];
#pragma unroll
      for (int n4 = 0; n4 < 4; ++n4) {
        float bb = ee_b2[(hh * 4 + n4) * 16 + cl_];
#pragma unroll
        for (int mt = 0; mt < 2; ++mt) { acc[mt][n4][0] = bb; acc[mt][n4][1] = bb; acc[mt][n4][2] = bb; acc[mt][n4][3] = bb; }
      }
#pragma unroll
      for (int c = 0; c < 4; ++c)
#pragma unroll
        for (int n4 = 0; n4 < 4; ++n4) {
          bf16x8 b = *(const bf16x8*)(WT_ee2 + ((hh * 4 + n4) * 16 + cl_) * 128 + c * 32 + ko);
#pragma unroll
          for (int mt = 0; mt < 2; ++mt)
            acc[mt][n4] = __builtin_amdgcn_mfma_f32_16x16x32_bf16(a2[c][mt], b, acc[mt][n4], 0, 0, 0);
        }
#pragma unroll
      for (int mt = 0; mt < 2; ++mt)
#pragma unroll
        for (int r = 0; r < 4; ++r) {
          int row = wrow + mt * 16 + g4 * 4 + r;
          float av = attS[row];
#pragma unroll
          for (int n4 = 0; n4 < 4; ++n4) {
            int col = (hh * 4 + n4) * 16 + cl_;
            ebuf[row * 128 + (col ^ ((row & 7) * 8))] = f2b(av * acc[mt][n4][r]);
          }
        }
    }
  }

  // ---- G: g = w_ef @ Wab ; z1 = relu(cn1[rn]+cn2[cn] + g) -> ebuf (nt-halved) ----
  {
    bf16x8 a2[4][2];
#pragma unroll
    for (int c = 0; c < 4; ++c)
#pragma unroll
      for (int mt = 0; mt < 2; ++mt) {
        int row = wrow + mt * 16 + cl_;
        a2[c][mt] = *(const bf16x8*)(ebuf + row * 128 + ((c * 32 + ko) ^ ((row & 7) * 8)));
      }
#pragma unroll
    for (int hh = 0; hh < 2; ++hh) {
      f32x4 acc[2][4];
#pragma unroll
      for (int n4 = 0; n4 < 4; ++n4)
#pragma unroll
        for (int mt = 0; mt < 2; ++mt) { acc[mt][n4][0] = 0.f; acc[mt][n4][1] = 0.f; acc[mt][n4][2] = 0.f; acc[mt][n4][3] = 0.f; }
#pragma unroll
      for (int c = 0; c < 4; ++c)
#pragma unroll
        for (int n4 = 0; n4 < 4; ++n4) {
          bf16x8 b = *(const bf16x8*)(WT_ab + ((hh * 4 + n4) * 16 + cl_) * 128 + c * 32 + ko);
#pragma unroll
          for (int mt = 0; mt < 2; ++mt)
            acc[mt][n4] = __builtin_amdgcn_mfma_f32_16x16x32_bf16(a2[c][mt], b, acc[mt][n4], 0, 0, 0);
        }
      u16x8 v1[4], v2[4];
#pragma unroll
      for (int k = 0; k < 4; ++k) {
        v1[k] = *(const u16x8*)(T1 + (long)rs * 256 + 128 + hh * 64 + cq + k * 8);
        v2[k] = *(const u16x8*)(T2 + (long)cs * 256 + 128 + hh * 64 + cq + k * 8);
      }
#pragma unroll
      for (int k = 0; k < 4; ++k) {
        u16x8 p;
#pragma unroll
        for (int i = 0; i < 8; ++i) p[i] = f2b(b2f(v1[k][i]) + b2f(v2[k][i]));
        *(u16x8*)(cstage + (srow & 31) * 64 + ((cq + k * 8) ^ ((srow & 7) * 8))) = p;
      }
#pragma unroll
      for (int mt = 0; mt < 2; ++mt)
#pragma unroll
        for (int r = 0; r < 4; ++r) {
          int row = wrow + mt * 16 + g4 * 4 + r;
#pragma unroll
          for (int n4 = 0; n4 < 4; ++n4) {
            int col = (hh * 4 + n4) * 16 + cl_;
            int cc = col - hh * 64;
            float v = acc[mt][n4][r] + b2f(cstage[(row & 31) * 64 + (cc ^ ((row & 7) * 8))]);
            ebuf[row * 128 + (col ^ ((row & 7) * 8))] = f2b(fmaxf(v, 0.f));
          }
        }
    }
  }

  // ---- clL2: z2 = relu(z1 @ cl_w2 + b2) (N=64) ----
  f32x4 acc2[2][4];
#pragma unroll
  for (int nt = 0; nt < 4; ++nt) {
    float bb = cl_b2[nt * 16 + cl_];
#pragma unroll
    for (int mt = 0; mt < 2; ++mt) { acc2[mt][nt][0] = bb; acc2[mt][nt][1] = bb; acc2[mt][nt][2] = bb; acc2[mt][nt][3] = bb; }
  }
#pragma unroll
  for (int c = 0; c < 4; ++c) {
    bf16x8 a[2], b[4];
#pragma unroll
    for (int mt = 0; mt < 2; ++mt) {
      int row = wrow + mt * 16 + cl_;
      a[mt] = *(const bf16x8*)(ebuf + row * 128 + ((c * 32 + ko) ^ ((row & 7) * 8)));
    }
#pragma unroll
    for (int nt = 0; nt < 4; ++nt)
      b[nt] = *(const bf16x8*)(WT_cl2 + (nt * 16 + cl_) * 128 + c * 32 + ko);
#pragma unroll
    for (int mt = 0; mt < 2; ++mt)
#pragma unroll
      for (int nt = 0; nt < 4; ++nt)
        acc2[mt][nt] = __builtin_amdgcn_mfma_f32_16x16x32_bf16(a[mt], b[nt], acc2[mt][nt], 0, 0, 0);
  }
#pragma unroll
  for (int mt = 0; mt < 2; ++mt)
#pragma unroll
    for (int r = 0; r < 4; ++r) {
      int row = wrow + mt * 16 + g4 * 4 + r;
#pragma unroll
      for (int nt = 0; nt < 4; ++nt) {
        int col = nt * 16 + cl_;
        ebuf[row * 128 + (col ^ ((row & 7) * 8))] = f2b(fmaxf(acc2[mt][nt][r], 0.f));
      }
    }
  __syncthreads();

  // ---- clL3: scatter to original edge order via eid ----
  if (t < 128) {
    long ge = eid[ebase + t];
    float o0 = cl_b3[0], o1 = cl_b3[1];
    for (int k8 = 0; k8 < 64; k8 += 8) {
      u16x8 v = *(const u16x8*)(ebuf + t * 128 + (k8 ^ ((t & 7) * 8)));
#pragma unroll
      for (int i = 0; i < 8; ++i) {
        float z = b2f(v[i]);
        o0 += z * cl_w3[(k8 + i) * 2];
        o1 += z * cl_w3[(k8 + i) * 2 + 1];
      }
    }
    *(float2*)(out + ge * 2) = make_float2(o0, o1);
  }
}

extern "C" void kernel_launch(void* const* d_in, const int* in_sizes, int n_in,
                              void* d_out, int out_size, void* d_ws, size_t ws_size,
                              hipStream_t stream) {
  (void)in_sizes; (void)n_in; (void)out_size; (void)ws_size;
  const float* x = (const float*)d_in[0];
  const int* ei = (const int*)d_in[1];
  const float* eattr = (const float*)d_in[2];
  const float* ne_w1 = (const float*)d_in[3];
  const float* ne_b1 = (const float*)d_in[4];
  const float* ne_w2 = (const float*)d_in[5];
  const float* ne_b2 = (const float*)d_in[6];
  const float* ee_w1 = (const float*)d_in[7];
  const float* ee_b1 = (const float*)d_in[8];
  const float* ee_w2 = (const float*)d_in[9];
  const float* ee_b2 = (const float*)d_in[10];
  const float* ea_w1 = (const float*)d_in[11];
  const float* ea_b1 = (const float*)d_in[12];
  const float* ea_w2 = (const float*)d_in[13];
  const float* ea_b2 = (const float*)d_in[14];
  const float* gcn_w = (const float*)d_in[15];
  const float* gcn_b = (const float*)d_in[16];
  const float* bn_g = (const float*)d_in[17];
  const float* bn_b = (const float*)d_in[18];
  const float* skip_w = (const float*)d_in[19];
  const float* skip_b = (const float*)d_in[20];
  const float* cl_w1 = (const float*)d_in[21];
  const float* cl_b1 = (const float*)d_in[22];
  const float* cl_w2 = (const float*)d_in[23];
  const float* cl_b2 = (const float*)d_in[24];
  const float* cl_w3 = (const float*)d_in[25];
  const float* cl_b3 = (const float*)d_in[26];
  float* out = (float*)d_out;

  // ws layout (bytes)
  char* ws = (char*)d_ws;
  u16* hb0 = (u16*)ws;                              // 12.8e6
  u16* hb1 = (u16*)(ws + 12800000);                 // 12.8e6 (unused now)
  float* A = (float*)(ws + 25600000);               // 25.6e6 f32 (skip out) / T1 overlay
  u16* mn = (u16*)(ws + 51200000);                  // 12.8e6 bf16 scaled message
  float* agg = (float*)(ws + 64000000);             // 25.6e6 / T2 overlay
  unsigned* deg = (unsigned*)(ws + 89600000);       // 200e3
  float* dinv = (float*)(ws + 89800000);            // 200e3
  double* sums = (double*)(ws + 90000000);          // 2048
  u16* WP = (u16*)(ws + 90002048);                  // 434176 B -> ends 90436224
  int* offs = (int*)(ws + 90436224);                // 200e3
  int* cursor = (int*)(ws + 90636224);              // 200e3
  int* bsum = (int*)(ws + 90836224);                // 1024
  int* boff = (int*)(ws + 90837248);                // 1024
  int* elr = (int*)(ws + 90838272);                 // 3.2e6
  int* ecn = (int*)(ws + 94038272);                 // 3.2e6
  int* eid = (int*)(ws + 97238272);                 // 3.2e6 (end ~100.44 MB)
  u16* T1 = (u16*)A;
  u16* T2 = (u16*)agg;
  (void)hb1;

  u16* WP_ne2 = WP;
  u16* WP_gcn = WP + 16384;
  u16* WP_skip = WP + 65536;
  u16* WP_t4 = WP + 98304;
  u16* WP_ab = WP + 163840;
  u16* WP_ee2 = WP + 180224;
  u16* WP_cl2 = WP + 196608;
  u16* WP_ee1 = WP + 204800;
  u16* WP_eae = WP + 208896;
  u16* WP_ne1 = WP + 212992;

  const int* col = ei + NE;
  const int NGB = (NN + 255) / 256;    // 196 (scan kernels)
  const int NGB128 = (NN + 127) / 128; // 391 (BM=128 GEMMs)

  k_prep<<<848, 256, 0, stream>>>(ea_w1, cl_w1, ee_w2, cl_w2, gcn_w, skip_w, ne_w2, ee_w1, ne_w1, WP);
  hipMemsetAsync(deg, 0, NN * sizeof(unsigned), stream);
  k_deg<<<(NE + 255) / 256, 256, 0, stream>>>(col, deg);
  k_scan1<<<NGB, 256, 0, stream>>>(deg, bsum);
  k_scan2<<<1, 256, 0, stream>>>(bsum, boff, NGB);
  k_scan3<<<NGB, 256, 0, stream>>>(deg, boff, offs, cursor, dinv);
  k_fill<<<(NE + 255) / 256, 256, 0, stream>>>(ei, cursor, elr, ecn, eid);

  k_nodeenc<<<NGB128, 256, 0, stream>>>(x, WP_ne1, WP_ne2, ne_b1, ne_b2, hb0);

  // layer 0: stage bf16 hb0; no skip GEMM
  k_gcnskip<0><<<NGB128, 256, 0, stream>>>(hb0, nullptr, nullptr, nullptr, nullptr,
                                           nullptr, nullptr, WP_gcn, nullptr, dinv, mn, A);
  hipMemsetAsync(sums, 0, 256 * sizeof(double), stream);
  k_agg<<<(NN + 63) / 64, 256, 0, stream>>>(offs, deg, elr, dinv, mn, gcn_b, agg, sums);

  // layer 1: stage h1 = relu(BN0(agg)); skip GEMM (Af1 = h1 @ skip_w0)
  k_gcnskip<1><<<NGB128, 256, 0, stream>>>(nullptr, agg, sums, bn_g, bn_b,
                                           nullptr, nullptr, WP_gcn + 16384, WP_skip, dinv, mn, A);
  hipMemsetAsync(sums, 0, 256 * sizeof(double), stream);
  k_agg<<<(NN + 63) / 64, 256, 0, stream>>>(offs, deg, elr, dinv, mn, gcn_b + H, agg, sums);

  // layer 2: stage h2 = relu(BN1(agg)) + Af1 + skip_b0; skip GEMM (Af2 = h2 @ skip_w1)
  k_gcnskip<2><<<NGB128, 256, 0, stream>>>(nullptr, agg, sums, bn_g + H, bn_b + H,
                                           A, skip_b, WP_gcn + 32768, WP_skip + 16384, dinv, mn, A);
  hipMemsetAsync(sums, 0, 256 * sizeof(double), stream);
  k_agg<<<(NN + 63) / 64, 256, 0, stream>>>(offs, deg, elr, dinv, mn, gcn_b + 2 * H, agg, sums);

  // node tables: stage h3 = relu(BN2(agg)) + Af2 + skip_b1; write T1/T2 (overlay A/agg)
  k_ntab<<<NGB128, 256, 0, stream>>>(agg, sums, bn_g + 2 * H, bn_b + 2 * H,
                                     A, skip_b + H, WP_t4, ea_b1, cl_b1, T1, T2);

  k_edge<<<NE / EPB, 256, 0, stream>>>(
      elr, ecn, eid, eattr, T1, T2, ee_b1, ee_b2, ea_w2, ea_b2,
      WP_ee1, WP_eae, WP_ee2, WP_ab, WP_cl2, cl_b2, cl_w3, cl_b3, out);
}

// Round 12
// 765.049 us; speedup vs baseline: 1.1857x; 1.1066x over previous
//
#include <hip/hip_runtime.h>
#include <math.h>

#define NN 50000
#define NE 800000
#define H 128

typedef short bf16x8 __attribute__((ext_vector_type(8)));
typedef unsigned short u16x8 __attribute__((ext_vector_type(8)));
typedef float f32x4 __attribute__((ext_vector_type(4)));
typedef unsigned short u16;

__device__ inline u16 f2b(float f) {
  unsigned u = __float_as_uint(f);
  return (u16)((u + 0x7FFF + ((u >> 16) & 1)) >> 16);
}
__device__ inline float b2f(u16 s) { return __uint_as_float(((unsigned)s) << 16); }

// =============== weight prep: bf16, transposed WT[n][k] = W[k][n] ===============
// WP element offsets:
//   ne2:0 gcn:16384(x3) skip:65536(x2)
//   t4:98304 (hn1,cn1,hn2,cn2 each 16384)
//   ab:163840 ee2:180224 cl2:196608(8192) ee1:204800([128][32]) eae:208896([128][32])
//   ne1:212992([128][32]) end:217088
__global__ void k_prep(const float* __restrict__ ea_w1, const float* __restrict__ cl_w1,
                       const float* __restrict__ ee_w2, const float* __restrict__ cl_w2,
                       const float* __restrict__ gcn_w, const float* __restrict__ skip_w,
                       const float* __restrict__ ne_w2, const float* __restrict__ ee_w1,
                       const float* __restrict__ ne_w1, u16* __restrict__ WP) {
  int idx = blockIdx.x * 256 + threadIdx.x;
  if (idx >= 217088) return;
  float v;
  if (idx < 16384) {            // ne2
    int n = idx >> 7, k = idx & 127;
    v = ne_w2[k * 128 + n];
  } else if (idx < 65536) {     // gcn
    int lo = idx - 16384; int i = lo >> 14; int n = (lo >> 7) & 127, k = lo & 127;
    v = gcn_w[i * 16384 + k * 128 + n];
  } else if (idx < 98304) {     // skip
    int lo = idx - 65536; int i = lo >> 14; int n = (lo >> 7) & 127, k = lo & 127;
    v = skip_w[i * 16384 + k * 128 + n];
  } else if (idx < 163840) {    // t4: hn1, cn1, hn2, cn2
    int lo = idx - 98304; int tab = lo >> 14; int n = (lo >> 7) & 127, k = lo & 127;
    if (tab == 0) v = ea_w1[k * 128 + n];
    else if (tab == 1) v = cl_w1[k * 128 + n];
    else if (tab == 2) v = ea_w1[(128 + k) * 128 + n];
    else v = cl_w1[(128 + k) * 128 + n];
  } else if (idx < 180224) {    // ab
    int lo = idx - 163840; int n = lo >> 7, k = lo & 127;
    v = cl_w1[k * 128 + n] + cl_w1[(128 + k) * 128 + n];
  } else if (idx < 196608) {    // ee2
    int lo = idx - 180224; int n = lo >> 7, k = lo & 127;
    v = ee_w2[k * 128 + n];
  } else if (idx < 204800) {    // cl2 [64][128]
    int lo = idx - 196608; int n = lo >> 7, k = lo & 127;
    v = cl_w2[k * 64 + n];
  } else if (idx < 208896) {    // ee1 [128][32] zero-padded K
    int lo = idx - 204800; int n = lo >> 5, k = lo & 31;
    v = (k < 10) ? ee_w1[k * 128 + n] : 0.f;
  } else if (idx < 212992) {    // eae [128][32] zero-padded K (ea_w1 rows 256..265)
    int lo = idx - 208896; int n = lo >> 5, k = lo & 31;
    v = (k < 10) ? ea_w1[(256 + k) * 128 + n] : 0.f;
  } else {                      // ne1 [128][32] zero-padded K
    int lo = idx - 212992; int n = lo >> 5, k = lo & 31;
    v = (k < 10) ? ne_w1[k * 128 + n] : 0.f;
  }
  WP[idx] = f2b(v);
}

// =============== fused node encoder: hb0 = relu(x@ne_w1+b1) @ ne_w2 + b2 ===============
__global__ __launch_bounds__(256, 2) void k_nodeenc(
    const float* __restrict__ x, const u16* __restrict__ WT1,
    const u16* __restrict__ WT2, const float* __restrict__ b1,
    const float* __restrict__ b2, u16* __restrict__ outB) {
  __shared__ u16 XL[128 * 32];
  __shared__ u16 As[128 * 128];
  int t = threadIdx.x;
  long base = (long)blockIdx.x * 128;
  for (int idx = t; idx < 128 * 32; idx += 256) {
    int row = idx >> 5, kk = idx & 31;
    long gr = base + row; if (gr >= NN) gr = 0;
    XL[idx] = (kk < 10) ? f2b(x[gr * 10 + kk]) : (u16)0;
  }
  __syncthreads();
  int l = t & 63, w = t >> 6;
  int wrow = w * 32;
  int cl_ = l & 15, g4 = l >> 4, ko = g4 * 8;
  // L1
  {
    bf16x8 a[2], b[8];
#pragma unroll
    for (int mt = 0; mt < 2; ++mt)
      a[mt] = *(const bf16x8*)(XL + (wrow + mt * 16 + cl_) * 32 + ko);
#pragma unroll
    for (int nt = 0; nt < 8; ++nt)
      b[nt] = *(const bf16x8*)(WT1 + (nt * 16 + cl_) * 32 + ko);
#pragma unroll
    for (int mt = 0; mt < 2; ++mt)
#pragma unroll
      for (int nt = 0; nt < 8; ++nt) {
        float bb = b1[nt * 16 + cl_];
        f32x4 ua;
        ua[0] = bb; ua[1] = bb; ua[2] = bb; ua[3] = bb;
        ua = __builtin_amdgcn_mfma_f32_16x16x32_bf16(a[mt], b[nt], ua, 0, 0, 0);
#pragma unroll
        for (int r = 0; r < 4; ++r) {
          int row = wrow + mt * 16 + g4 * 4 + r;
          int col = nt * 16 + cl_;
          As[row * 128 + (col ^ ((row & 7) * 8))] = f2b(fmaxf(ua[r], 0.f));
        }
      }
  }
  // L2 (wave-local As rows)
  f32x4 acc[2][8];
#pragma unroll
  for (int nt = 0; nt < 8; ++nt) {
    float bb = b2[nt * 16 + cl_];
#pragma unroll
    for (int mt = 0; mt < 2; ++mt) { acc[mt][nt][0] = bb; acc[mt][nt][1] = bb; acc[mt][nt][2] = bb; acc[mt][nt][3] = bb; }
  }
#pragma unroll
  for (int c = 0; c < 4; ++c) {
    bf16x8 a[2], b[8];
#pragma unroll
    for (int mt = 0; mt < 2; ++mt) {
      int row = wrow + mt * 16 + cl_;
      a[mt] = *(const bf16x8*)(As + row * 128 + ((c * 32 + ko) ^ ((row & 7) * 8)));
    }
#pragma unroll
    for (int nt = 0; nt < 8; ++nt)
      b[nt] = *(const bf16x8*)(WT2 + (nt * 16 + cl_) * 128 + c * 32 + ko);
#pragma unroll
    for (int mt = 0; mt < 2; ++mt)
#pragma unroll
      for (int nt = 0; nt < 8; ++nt)
        acc[mt][nt] = __builtin_amdgcn_mfma_f32_16x16x32_bf16(a[mt], b[nt], acc[mt][nt], 0, 0, 0);
  }
#pragma unroll
  for (int mt = 0; mt < 2; ++mt)
#pragma unroll
    for (int r = 0; r < 4; ++r) {
      long row = base + wrow + mt * 16 + g4 * 4 + r;
      if (row >= NN) continue;
#pragma unroll
      for (int nt = 0; nt < 8; ++nt)
        outB[row * 128 + nt * 16 + cl_] = f2b(acc[mt][nt][r]);
    }
}

// =============== gcn(+skip) GEMM with fused BN staging ===============
// MODE 0: stage bf16 hb directly. MODE 1: stage relu(BN(agg)). MODE 2: + AfIn + skipb.
template <int MODE>
__global__ __launch_bounds__(256, 2) void k_gcnskip(
    const u16* __restrict__ hbin,
    const float* __restrict__ agg, const double* __restrict__ sums,
    const float* __restrict__ g, const float* __restrict__ b,
    const float* __restrict__ AfIn, const float* __restrict__ skipb,
    const u16* __restrict__ WTg, const u16* __restrict__ WTs,
    const float* __restrict__ dinv, u16* __restrict__ mn, float* __restrict__ Af) {
  __shared__ u16 As[128 * 128];
  __shared__ float sc_[128], sh_[128];
  int t = threadIdx.x;
  long base = (long)blockIdx.x * 128;
  if (MODE > 0) {
    if (t < 128) {
      double mu = sums[t] * (1.0 / NN);
      double var = sums[128 + t] * (1.0 / NN) - mu * mu;
      float inv = (float)(1.0 / sqrt(var + 1e-5));
      float sc = inv * g[t];
      sc_[t] = sc;
      sh_[t] = b[t] - (float)mu * sc;
    }
    __syncthreads();
    for (int idx = t; idx < 128 * 16; idx += 256) {
      int row = idx >> 4, k8 = (idx & 15) * 8;
      long gr = base + row; if (gr >= NN) gr = 0;
      float4 a0 = *(const float4*)(agg + gr * 128 + k8);
      float4 a1 = *(const float4*)(agg + gr * 128 + k8 + 4);
      float v[8] = {a0.x, a0.y, a0.z, a0.w, a1.x, a1.y, a1.z, a1.w};
      float f[8] = {0, 0, 0, 0, 0, 0, 0, 0};
      if (MODE == 2) {
        float4 f0 = *(const float4*)(AfIn + gr * 128 + k8);
        float4 f1 = *(const float4*)(AfIn + gr * 128 + k8 + 4);
        f[0] = f0.x; f[1] = f0.y; f[2] = f0.z; f[3] = f0.w;
        f[4] = f1.x; f[5] = f1.y; f[6] = f1.z; f[7] = f1.w;
      }
      u16x8 p;
#pragma unroll
      for (int k = 0; k < 8; ++k) {
        int j = k8 + k;
        float val = fmaxf(v[k] * sc_[j] + sh_[j], 0.f);
        if (MODE == 2) val += f[k] + skipb[j];
        p[k] = f2b(val);
      }
      *(u16x8*)(As + row * 128 + (k8 ^ ((row & 7) * 8))) = p;
    }
  } else {
    for (int idx = t; idx < 128 * 16; idx += 256) {
      int row = idx >> 4, k8 = (idx & 15) * 8;
      long gr = base + row; if (gr >= NN) gr = 0;
      uint4 v = *(const uint4*)(hbin + gr * 128 + k8);
      *(uint4*)(As + row * 128 + (k8 ^ ((row & 7) * 8))) = v;
    }
  }
  __syncthreads();
  int l = t & 63, w = t >> 6;
  int wrow = w * 32;
  int cl_ = l & 15, g4 = l >> 4, ko = g4 * 8;
  // pass 1: gcn -> mn (dinv-premultiplied bf16)
  {
    f32x4 acc[2][8];
#pragma unroll
    for (int nt = 0; nt < 8; ++nt)
#pragma unroll
      for (int mt = 0; mt < 2; ++mt) { acc[mt][nt][0] = 0.f; acc[mt][nt][1] = 0.f; acc[mt][nt][2] = 0.f; acc[mt][nt][3] = 0.f; }
#pragma unroll
    for (int c = 0; c < 4; ++c) {
      bf16x8 a[2], b8[8];
#pragma unroll
      for (int mt = 0; mt < 2; ++mt) {
        int row = wrow + mt * 16 + cl_;
        a[mt] = *(const bf16x8*)(As + row * 128 + ((c * 32 + ko) ^ ((row & 7) * 8)));
      }
#pragma unroll
      for (int nt = 0; nt < 8; ++nt)
        b8[nt] = *(const bf16x8*)(WTg + (nt * 16 + cl_) * 128 + c * 32 + ko);
#pragma unroll
      for (int mt = 0; mt < 2; ++mt)
#pragma unroll
        for (int nt = 0; nt < 8; ++nt)
          acc[mt][nt] = __builtin_amdgcn_mfma_f32_16x16x32_bf16(a[mt], b8[nt], acc[mt][nt], 0, 0, 0);
    }
#pragma unroll
    for (int mt = 0; mt < 2; ++mt)
#pragma unroll
      for (int r = 0; r < 4; ++r) {
        long row = base + wrow + mt * 16 + g4 * 4 + r;
        if (row >= NN) continue;
        float dv = dinv[row];
#pragma unroll
        for (int nt = 0; nt < 8; ++nt)
          mn[row * 128 + nt * 16 + cl_] = f2b(dv * acc[mt][nt][r]);
      }
  }
  // pass 2: skip -> Af (f32); As read-only, no barrier needed
  if (WTs) {
    f32x4 acc[2][8];
#pragma unroll
    for (int nt = 0; nt < 8; ++nt)
#pragma unroll
      for (int mt = 0; mt < 2; ++mt) { acc[mt][nt][0] = 0.f; acc[mt][nt][1] = 0.f; acc[mt][nt][2] = 0.f; acc[mt][nt][3] = 0.f; }
#pragma unroll
    for (int c = 0; c < 4; ++c) {
      bf16x8 a[2], b8[8];
#pragma unroll
      for (int mt = 0; mt < 2; ++mt) {
        int row = wrow + mt * 16 + cl_;
        a[mt] = *(const bf16x8*)(As + row * 128 + ((c * 32 + ko) ^ ((row & 7) * 8)));
      }
#pragma unroll
      for (int nt = 0; nt < 8; ++nt)
        b8[nt] = *(const bf16x8*)(WTs + (nt * 16 + cl_) * 128 + c * 32 + ko);
#pragma unroll
      for (int mt = 0; mt < 2; ++mt)
#pragma unroll
        for (int nt = 0; nt < 8; ++nt)
          acc[mt][nt] = __builtin_amdgcn_mfma_f32_16x16x32_bf16(a[mt], b8[nt], acc[mt][nt], 0, 0, 0);
    }
#pragma unroll
    for (int mt = 0; mt < 2; ++mt)
#pragma unroll
      for (int r = 0; r < 4; ++r) {
        long row = base + wrow + mt * 16 + g4 * 4 + r;
        if (row >= NN) continue;
#pragma unroll
        for (int nt = 0; nt < 8; ++nt)
          Af[row * 128 + nt * 16 + cl_] = acc[mt][nt][r];
      }
  }
}

// =============== 4-table GEMM with fused BN+skip staging (h3) ===============
__global__ __launch_bounds__(256, 2) void k_ntab(
    const float* __restrict__ agg, const double* __restrict__ sums,
    const float* __restrict__ g, const float* __restrict__ b,
    const float* __restrict__ AfIn, const float* __restrict__ skipb,
    const u16* __restrict__ WPt4,
    const float* __restrict__ ea_b1, const float* __restrict__ cl_b1,
    u16* __restrict__ T1, u16* __restrict__ T2) {
  __shared__ u16 As[128 * 128];
  __shared__ float sc_[128], sh_[128];
  int t = threadIdx.x;
  long base = (long)blockIdx.x * 128;
  if (t < 128) {
    double mu = sums[t] * (1.0 / NN);
    double var = sums[128 + t] * (1.0 / NN) - mu * mu;
    float inv = (float)(1.0 / sqrt(var + 1e-5));
    float sc = inv * g[t];
    sc_[t] = sc;
    sh_[t] = b[t] - (float)mu * sc;
  }
  __syncthreads();
  for (int idx = t; idx < 128 * 16; idx += 256) {
    int row = idx >> 4, k8 = (idx & 15) * 8;
    long gr = base + row; if (gr >= NN) gr = 0;
    float4 a0 = *(const float4*)(agg + gr * 128 + k8);
    float4 a1 = *(const float4*)(agg + gr * 128 + k8 + 4);
    float4 f0 = *(const float4*)(AfIn + gr * 128 + k8);
    float4 f1 = *(const float4*)(AfIn + gr * 128 + k8 + 4);
    float v[8] = {a0.x, a0.y, a0.z, a0.w, a1.x, a1.y, a1.z, a1.w};
    float f[8] = {f0.x, f0.y, f0.z, f0.w, f1.x, f1.y, f1.z, f1.w};
    u16x8 p;
#pragma unroll
    for (int k = 0; k < 8; ++k) {
      int j = k8 + k;
      float val = fmaxf(v[k] * sc_[j] + sh_[j], 0.f) + f[k] + skipb[j];
      p[k] = f2b(val);
    }
    *(u16x8*)(As + row * 128 + (k8 ^ ((row & 7) * 8))) = p;
  }
  __syncthreads();
  int l = t & 63, w = t >> 6;
  int wrow = w * 32;
  int cl_ = l & 15, g4 = l >> 4, ko = g4 * 8;
  for (int y = 0; y < 4; ++y) {
    const u16* WT = WPt4 + y * 16384;
    const float* bias = (y == 0) ? ea_b1 : ((y == 1) ? cl_b1 : nullptr);
    u16* outT = (y < 2) ? T1 : T2;
    int colOff = (y & 1) * 128;
    f32x4 acc[2][8];
#pragma unroll
    for (int nt = 0; nt < 8; ++nt) {
      float bb = bias ? bias[nt * 16 + cl_] : 0.f;
#pragma unroll
      for (int mt = 0; mt < 2; ++mt) { acc[mt][nt][0] = bb; acc[mt][nt][1] = bb; acc[mt][nt][2] = bb; acc[mt][nt][3] = bb; }
    }
#pragma unroll
    for (int c = 0; c < 4; ++c) {
      bf16x8 a[2], b8[8];
#pragma unroll
      for (int mt = 0; mt < 2; ++mt) {
        int row = wrow + mt * 16 + cl_;
        a[mt] = *(const bf16x8*)(As + row * 128 + ((c * 32 + ko) ^ ((row & 7) * 8)));
      }
#pragma unroll
      for (int nt = 0; nt < 8; ++nt)
        b8[nt] = *(const bf16x8*)(WT + (nt * 16 + cl_) * 128 + c * 32 + ko);
#pragma unroll
      for (int mt = 0; mt < 2; ++mt)
#pragma unroll
        for (int nt = 0; nt < 8; ++nt)
          acc[mt][nt] = __builtin_amdgcn_mfma_f32_16x16x32_bf16(a[mt], b8[nt], acc[mt][nt], 0, 0, 0);
    }
#pragma unroll
    for (int mt = 0; mt < 2; ++mt)
#pragma unroll
      for (int r = 0; r < 4; ++r) {
        long row = base + wrow + mt * 16 + g4 * 4 + r;
        if (row >= NN) continue;
#pragma unroll
        for (int nt = 0; nt < 8; ++nt)
          outT[row * 256 + colOff + nt * 16 + cl_] = f2b(acc[mt][nt][r]);
      }
  }
}

// =============== degree ===============
__global__ void k_deg(const int* __restrict__ col, unsigned* __restrict__ deg) {
  int e = blockIdx.x * 256 + threadIdx.x;
  if (e < NE) atomicAdd(&deg[col[e]], 1u);
}

// =============== CSR build ===============
__global__ __launch_bounds__(256) void k_scan1(const unsigned* __restrict__ deg,
                                               int* __restrict__ bsum) {
  __shared__ int s[256];
  int t = threadIdx.x, v = blockIdx.x * 256 + t;
  s[t] = (v < NN) ? (int)deg[v] : 0;
  __syncthreads();
  for (int off = 128; off > 0; off >>= 1) {
    if (t < off) s[t] += s[t + off];
    __syncthreads();
  }
  if (t == 0) bsum[blockIdx.x] = s[0];
}
__global__ __launch_bounds__(256) void k_scan2(const int* __restrict__ bsum,
                                               int* __restrict__ boff, int nb) {
  __shared__ int s[256];
  int t = threadIdx.x;
  int v = (t < nb) ? bsum[t] : 0;
  s[t] = v;
  __syncthreads();
  for (int off = 1; off < 256; off <<= 1) {
    int x = (t >= off) ? s[t - off] : 0;
    __syncthreads();
    s[t] += x;
    __syncthreads();
  }
  if (t < nb) boff[t] = s[t] - v;
}
__global__ __launch_bounds__(256) void k_scan3(const unsigned* __restrict__ deg,
                                               const int* __restrict__ boff,
                                               int* __restrict__ offs, int* __restrict__ cursor,
                                               float* __restrict__ dinv) {
  __shared__ int s[256];
  int t = threadIdx.x, v = blockIdx.x * 256 + t;
  int d = (v < NN) ? (int)deg[v] : 0;
  s[t] = d;
  __syncthreads();
  for (int off = 1; off < 256; off <<= 1) {
    int x = (t >= off) ? s[t - off] : 0;
    __syncthreads();
    s[t] += x;
    __syncthreads();
  }
  int excl = s[t] - d + boff[blockIdx.x];
  if (v < NN) {
    offs[v] = excl; cursor[v] = excl;
    dinv[v] = 1.0f / sqrtf((float)(d + 1));
  }
}
__global__ void k_fill(const int* __restrict__ ei, int* __restrict__ cursor,
                       int* __restrict__ elr, int* __restrict__ ecn, int* __restrict__ eid) {
  int e = blockIdx.x * 256 + threadIdx.x;
  if (e < NE) {
    int c = ei[NE + e];
    int pos = atomicAdd(&cursor[c], 1);
    elr[pos] = ei[e];
    ecn[pos] = c;
    eid[pos] = e;
  }
}

// =============== CSR aggregate + fused BN stats ===============
// 4-way unrolled gather: the inner loop was a SERIAL latency chain (one ~600-900cy
// L3 gather per iteration, acc-dependent). Issuing 4 independent u16x8 loads
// back-to-back puts 4 in flight; accumulation order preserved (bitwise-identical).
__global__ __launch_bounds__(256) void k_agg(
    const int* __restrict__ offs, const unsigned* __restrict__ deg,
    const int* __restrict__ elr, const float* __restrict__ dinv,
    const u16* __restrict__ mn, const float* __restrict__ gb,
    float* __restrict__ agg, double* __restrict__ sums) {
  __shared__ float s_lds[16][128];
  __shared__ float q_lds[16][128];
  int t = threadIdx.x;
  int slot = t >> 4;
  int j8 = (t & 15) * 8;
  float ps[8], pq[8];
#pragma unroll
  for (int k = 0; k < 8; ++k) { ps[k] = 0.f; pq[k] = 0.f; }
  int vbase = blockIdx.x * 64;
  for (int nn = 0; nn < 4; ++nn) {
    int v = vbase + nn * 16 + slot;
    if (v < NN) {
      float acc[8];
      u16x8 m0 = *(const u16x8*)(mn + (long)v * 128 + j8);
#pragma unroll
      for (int k = 0; k < 8; ++k) acc[k] = b2f(m0[k]);
      int start = offs[v];
      int cnt = (int)deg[v];
      int i = 0;
      for (; i + 4 <= cnt; i += 4) {
        int n0 = elr[start + i], n1 = elr[start + i + 1];
        int n2 = elr[start + i + 2], n3 = elr[start + i + 3];
        u16x8 g0 = *(const u16x8*)(mn + (long)n0 * 128 + j8);
        u16x8 g1 = *(const u16x8*)(mn + (long)n1 * 128 + j8);
        u16x8 g2 = *(const u16x8*)(mn + (long)n2 * 128 + j8);
        u16x8 g3 = *(const u16x8*)(mn + (long)n3 * 128 + j8);
#pragma unroll
        for (int k = 0; k < 8; ++k) acc[k] += b2f(g0[k]);
#pragma unroll
        for (int k = 0; k < 8; ++k) acc[k] += b2f(g1[k]);
#pragma unroll
        for (int k = 0; k < 8; ++k) acc[k] += b2f(g2[k]);
#pragma unroll
        for (int k = 0; k < 8; ++k) acc[k] += b2f(g3[k]);
      }
      for (; i < cnt; ++i) {
        u16x8 m = *(const u16x8*)(mn + (long)elr[start + i] * 128 + j8);
#pragma unroll
        for (int k = 0; k < 8; ++k) acc[k] += b2f(m[k]);
      }
      float dv = dinv[v];
#pragma unroll
      for (int k = 0; k < 8; ++k) {
        acc[k] = dv * acc[k] + gb[j8 + k];
        ps[k] += acc[k];
        pq[k] += acc[k] * acc[k];
      }
      *(float4*)(agg + (long)v * 128 + j8) = make_float4(acc[0], acc[1], acc[2], acc[3]);
      *(float4*)(agg + (long)v * 128 + j8 + 4) = make_float4(acc[4], acc[5], acc[6], acc[7]);
    }
  }
#pragma unroll
  for (int k = 0; k < 8; ++k) { s_lds[slot][j8 + k] = ps[k]; q_lds[slot][j8 + k] = pq[k]; }
  __syncthreads();
  if (t < 128) {
    float s = 0.f;
#pragma unroll
    for (int sl = 0; sl < 16; ++sl) s += s_lds[sl][t];
    atomicAdd(&sums[t], (double)s);
  } else {
    int j = t - 128;
    float q = 0.f;
#pragma unroll
    for (int sl = 0; sl < 16; ++sl) q += q_lds[sl][j];
    atomicAdd(&sums[128 + j], (double)q);
  }
}

// =============== fused per-edge head (all GEMMs on MFMA) ===============
// EXACT r8 structure (413 us): CSR-ordered edges (T2-side L2-resident).
#define EPB 128
__global__ __launch_bounds__(256, 2) void k_edge(
    const int* __restrict__ elr, const int* __restrict__ ecn, const int* __restrict__ eid,
    const float* __restrict__ eaf,
    const u16* __restrict__ T1, const u16* __restrict__ T2,
    const float* __restrict__ ee_b1, const float* __restrict__ ee_b2,
    const float* __restrict__ ea_w2, const float* __restrict__ ea_b2,
    const u16* __restrict__ WT_ee1, const u16* __restrict__ WT_eae,
    const u16* __restrict__ WT_ee2, const u16* __restrict__ WT_ab,
    const u16* __restrict__ WT_cl2,
    const float* __restrict__ cl_b2, const float* __restrict__ cl_w3,
    const float* __restrict__ cl_b3,
    float* __restrict__ out) {
  __shared__ u16 ebuf[128 * 128];   // P -> U -> w_ef -> z1 -> z2
  __shared__ u16 ustage[8192];      // EAs[128][32] then 4x per-wave cstage[32][64]
  __shared__ float attP[256];
  __shared__ float attS[128];

  int t = threadIdx.x;
  long ebase = (long)blockIdx.x * EPB;
  int e = t & 127, half = t >> 7;
  int jb0 = half * 64;
  int rn = elr[ebase + e];
  int cn = ecn[ebase + e];

  int l = t & 63, w = t >> 6;
  int wrow = w * 32;
  int cl_ = l & 15, g4 = l >> 4, ko = g4 * 8;

  int srow = wrow + (l >> 1);
  int cq = (l & 1) * 32;
  int rs = elr[ebase + srow];
  int cs = ecn[ebase + srow];
  u16* cstage = ustage + w * 2048;  // wave-local 32x64 slice

  // ---- stage EA (zero-padded K=32), gathered via eid ----
  {
    int k0 = half * 16;
    long ge = eid[ebase + e];
    const float* src = eaf + ge * 10;
#pragma unroll
    for (int k = 0; k < 16; ++k) {
      int kk = k0 + k;
      ustage[e * 32 + kk] = (kk < 10) ? f2b(src[kk]) : (u16)0;
    }
  }
  __syncthreads();  // EAs ready

  // ---- MFMA-P: P = EA @ eaeT -> ebuf ----
  {
    bf16x8 aEA[2];
#pragma unroll
    for (int mt = 0; mt < 2; ++mt)
      aEA[mt] = *(const bf16x8*)(ustage + (wrow + mt * 16 + cl_) * 32 + ko);
    bf16x8 b[8];
#pragma unroll
    for (int nt = 0; nt < 8; ++nt)
      b[nt] = *(const bf16x8*)(WT_eae + (nt * 16 + cl_) * 32 + ko);
#pragma unroll
    for (int mt = 0; mt < 2; ++mt)
#pragma unroll
      for (int nt = 0; nt < 8; ++nt) {
        f32x4 pa = {0.f, 0.f, 0.f, 0.f};
        pa = __builtin_amdgcn_mfma_f32_16x16x32_bf16(aEA[mt], b[nt], pa, 0, 0, 0);
#pragma unroll
        for (int r = 0; r < 4; ++r) {
          int row = wrow + mt * 16 + g4 * 4 + r;
          int col = nt * 16 + cl_;
          ebuf[row * 128 + (col ^ ((row & 7) * 8))] = f2b(pa[r]);
        }
      }
  }
  __syncthreads();  // P visible

  // ---- att scalar (VALU): sigmoid(relu(h1+h2+P).w2 + b2) ----
  {
    float s = 0.f;
    for (int jb = jb0; jb < jb0 + 64; jb += 8) {
      u16x8 h1 = *(const u16x8*)(T1 + (long)rn * 256 + jb);
      u16x8 h2 = *(const u16x8*)(T2 + (long)cn * 256 + jb);
      u16x8 pp = *(const u16x8*)(ebuf + e * 128 + (jb ^ ((e & 7) * 8)));
#pragma unroll
      for (int i = 0; i < 8; ++i)
        s += fmaxf(b2f(h1[i]) + b2f(h2[i]) + b2f(pp[i]), 0.f) * ea_w2[jb + i];
    }
    attP[half * 128 + e] = s;
  }
  __syncthreads();  // attP done; ebuf free

  if (t < 128) attS[t] = 1.f / (1.f + __expf(-(attP[t] + attP[128 + t] + ea_b2[0])));

  // ---- MFMA-U: U = relu(EA @ ee1T + b1) -> ebuf ----
  {
    bf16x8 aEA[2];
#pragma unroll
    for (int mt = 0; mt < 2; ++mt)
      aEA[mt] = *(const bf16x8*)(ustage + (wrow + mt * 16 + cl_) * 32 + ko);
    bf16x8 b[8];
#pragma unroll
    for (int nt = 0; nt < 8; ++nt)
      b[nt] = *(const bf16x8*)(WT_ee1 + (nt * 16 + cl_) * 32 + ko);
#pragma unroll
    for (int mt = 0; mt < 2; ++mt)
#pragma unroll
      for (int nt = 0; nt < 8; ++nt) {
        float bb = ee_b1[nt * 16 + cl_];
        f32x4 ua;
        ua[0] = bb; ua[1] = bb; ua[2] = bb; ua[3] = bb;
        ua = __builtin_amdgcn_mfma_f32_16x16x32_bf16(aEA[mt], b[nt], ua, 0, 0, 0);
#pragma unroll
        for (int r = 0; r < 4; ++r) {
          int row = wrow + mt * 16 + g4 * 4 + r;
          int col = nt * 16 + cl_;
          ebuf[row * 128 + (col ^ ((row & 7) * 8))] = f2b(fmaxf(ua[r], 0.f));
        }
      }
  }
  __syncthreads();  // attS visible to all (U is wave-local)

  // ---- eeL2: F = U @ ee_w2 + b2 ; w_ef = att*F -> ebuf (nt-halved, A hoisted) ----
  {
    bf16x8 a2[4][2];
#pragma unroll
    for (int c = 0; c < 4; ++c)
#pragma unroll
      for (int mt = 0; mt < 2; ++mt) {
        int row = wrow + mt * 16 + cl_;
        a2[c][mt] = *(const bf16x8*)(ebuf + row * 128 + ((c * 32 + ko) ^ ((row & 7) * 8)));
      }
#pragma unroll
    for (int hh = 0; hh < 2; ++hh) {
      f32x4 acc[2][4];
#pragma unroll
      for (int n4 = 0; n4 < 4; ++n4) {
        float bb = ee_b2[(hh * 4 + n4) * 16 + cl_];
#pragma unroll
        for (int mt = 0; mt < 2; ++mt) { acc[mt][n4][0] = bb; acc[mt][n4][1] = bb; acc[mt][n4][2] = bb; acc[mt][n4][3] = bb; }
      }
#pragma unroll
      for (int c = 0; c < 4; ++c)
#pragma unroll
        for (int n4 = 0; n4 < 4; ++n4) {
          bf16x8 b = *(const bf16x8*)(WT_ee2 + ((hh * 4 + n4) * 16 + cl_) * 128 + c * 32 + ko);
#pragma unroll
          for (int mt = 0; mt < 2; ++mt)
            acc[mt][n4] = __builtin_amdgcn_mfma_f32_16x16x32_bf16(a2[c][mt], b, acc[mt][n4], 0, 0, 0);
        }
#pragma unroll
      for (int mt = 0; mt < 2; ++mt)
#pragma unroll
        for (int r = 0; r < 4; ++r) {
          int row = wrow + mt * 16 + g4 * 4 + r;
          float av = attS[row];
#pragma unroll
          for (int n4 = 0; n4 < 4; ++n4) {
            int col = (hh * 4 + n4) * 16 + cl_;
            ebuf[row * 128 + (col ^ ((row & 7) * 8))] = f2b(av * acc[mt][n4][r]);
          }
        }
    }
  }

  // ---- G: g = w_ef @ Wab ; z1 = relu(cn1[rn]+cn2[cn] + g) -> ebuf (nt-halved) ----
  {
    bf16x8 a2[4][2];
#pragma unroll
    for (int c = 0; c < 4; ++c)
#pragma unroll
      for (int mt = 0; mt < 2; ++mt) {
        int row = wrow + mt * 16 + cl_;
        a2[c][mt] = *(const bf16x8*)(ebuf + row * 128 + ((c * 32 + ko) ^ ((row & 7) * 8)));
      }
#pragma unroll
    for (int hh = 0; hh < 2; ++hh) {
      f32x4 acc[2][4];
#pragma unroll
      for (int n4 = 0; n4 < 4; ++n4)
#pragma unroll
        for (int mt = 0; mt < 2; ++mt) { acc[mt][n4][0] = 0.f; acc[mt][n4][1] = 0.f; acc[mt][n4][2] = 0.f; acc[mt][n4][3] = 0.f; }
#pragma unroll
      for (int c = 0; c < 4; ++c)
#pragma unroll
        for (int n4 = 0; n4 < 4; ++n4) {
          bf16x8 b = *(const bf16x8*)(WT_ab + ((hh * 4 + n4) * 16 + cl_) * 128 + c * 32 + ko);
#pragma unroll
          for (int mt = 0; mt < 2; ++mt)
            acc[mt][n4] = __builtin_amdgcn_mfma_f32_16x16x32_bf16(a2[c][mt], b, acc[mt][n4], 0, 0, 0);
        }
      u16x8 v1[4], v2[4];
#pragma unroll
      for (int k = 0; k < 4; ++k) {
        v1[k] = *(const u16x8*)(T1 + (long)rs * 256 + 128 + hh * 64 + cq + k * 8);
        v2[k] = *(const u16x8*)(T2 + (long)cs * 256 + 128 + hh * 64 + cq + k * 8);
      }
#pragma unroll
      for (int k = 0; k < 4; ++k) {
        u16x8 p;
#pragma unroll
        for (int i = 0; i < 8; ++i) p[i] = f2b(b2f(v1[k][i]) + b2f(v2[k][i]));
        *(u16x8*)(cstage + (srow & 31) * 64 + ((cq + k * 8) ^ ((srow & 7) * 8))) = p;
      }
#pragma unroll
      for (int mt = 0; mt < 2; ++mt)
#pragma unroll
        for (int r = 0; r < 4; ++r) {
          int row = wrow + mt * 16 + g4 * 4 + r;
#pragma unroll
          for (int n4 = 0; n4 < 4; ++n4) {
            int col = (hh * 4 + n4) * 16 + cl_;
            int cc = col - hh * 64;
            float v = acc[mt][n4][r] + b2f(cstage[(row & 31) * 64 + (cc ^ ((row & 7) * 8))]);
            ebuf[row * 128 + (col ^ ((row & 7) * 8))] = f2b(fmaxf(v, 0.f));
          }
        }
    }
  }

  // ---- clL2: z2 = relu(z1 @ cl_w2 + b2) (N=64) ----
  f32x4 acc2[2][4];
#pragma unroll
  for (int nt = 0; nt < 4; ++nt) {
    float bb = cl_b2[nt * 16 + cl_];
#pragma unroll
    for (int mt = 0; mt < 2; ++mt) { acc2[mt][nt][0] = bb; acc2[mt][nt][1] = bb; acc2[mt][nt][2] = bb; acc2[mt][nt][3] = bb; }
  }
#pragma unroll
  for (int c = 0; c < 4; ++c) {
    bf16x8 a[2], b[4];
#pragma unroll
    for (int mt = 0; mt < 2; ++mt) {
      int row = wrow + mt * 16 + cl_;
      a[mt] = *(const bf16x8*)(ebuf + row * 128 + ((c * 32 + ko) ^ ((row & 7) * 8)));
    }
#pragma unroll
    for (int nt = 0; nt < 4; ++nt)
      b[nt] = *(const bf16x8*)(WT_cl2 + (nt * 16 + cl_) * 128 + c * 32 + ko);
#pragma unroll
    for (int mt = 0; mt < 2; ++mt)
#pragma unroll
      for (int nt = 0; nt < 4; ++nt)
        acc2[mt][nt] = __builtin_amdgcn_mfma_f32_16x16x32_bf16(a[mt], b[nt], acc2[mt][nt], 0, 0, 0);
  }
#pragma unroll
  for (int mt = 0; mt < 2; ++mt)
#pragma unroll
    for (int r = 0; r < 4; ++r) {
      int row = wrow + mt * 16 + g4 * 4 + r;
#pragma unroll
      for (int nt = 0; nt < 4; ++nt) {
        int col = nt * 16 + cl_;
        ebuf[row * 128 + (col ^ ((row & 7) * 8))] = f2b(fmaxf(acc2[mt][nt][r], 0.f));
      }
    }
  __syncthreads();

  // ---- clL3: scatter to original edge order via eid ----
  if (t < 128) {
    long ge = eid[ebase + t];
    float o0 = cl_b3[0], o1 = cl_b3[1];
    for (int k8 = 0; k8 < 64; k8 += 8) {
      u16x8 v = *(const u16x8*)(ebuf + t * 128 + (k8 ^ ((t & 7) * 8)));
#pragma unroll
      for (int i = 0; i < 8; ++i) {
        float z = b2f(v[i]);
        o0 += z * cl_w3[(k8 + i) * 2];
        o1 += z * cl_w3[(k8 + i) * 2 + 1];
      }
    }
    *(float2*)(out + ge * 2) = make_float2(o0, o1);
  }
}

extern "C" void kernel_launch(void* const* d_in, const int* in_sizes, int n_in,
                              void* d_out, int out_size, void* d_ws, size_t ws_size,
                              hipStream_t stream) {
  (void)in_sizes; (void)n_in; (void)out_size; (void)ws_size;
  const float* x = (const float*)d_in[0];
  const int* ei = (const int*)d_in[1];
  const float* eattr = (const float*)d_in[2];
  const float* ne_w1 = (const float*)d_in[3];
  const float* ne_b1 = (const float*)d_in[4];
  const float* ne_w2 = (const float*)d_in[5];
  const float* ne_b2 = (const float*)d_in[6];
  const float* ee_w1 = (const float*)d_in[7];
  const float* ee_b1 = (const float*)d_in[8];
  const float* ee_w2 = (const float*)d_in[9];
  const float* ee_b2 = (const float*)d_in[10];
  const float* ea_w1 = (const float*)d_in[11];
  const float* ea_b1 = (const float*)d_in[12];
  const float* ea_w2 = (const float*)d_in[13];
  const float* ea_b2 = (const float*)d_in[14];
  const float* gcn_w = (const float*)d_in[15];
  const float* gcn_b = (const float*)d_in[16];
  const float* bn_g = (const float*)d_in[17];
  const float* bn_b = (const float*)d_in[18];
  const float* skip_w = (const float*)d_in[19];
  const float* skip_b = (const float*)d_in[20];
  const float* cl_w1 = (const float*)d_in[21];
  const float* cl_b1 = (const float*)d_in[22];
  const float* cl_w2 = (const float*)d_in[23];
  const float* cl_b2 = (const float*)d_in[24];
  const float* cl_w3 = (const float*)d_in[25];
  const float* cl_b3 = (const float*)d_in[26];
  float* out = (float*)d_out;

  // ws layout (bytes): deg and sums3 adjacent so ONE memset zeroes both (saves 3
  // dispatches vs per-layer sums memsets; each layer gets its own 2048 B sums buffer).
  char* ws = (char*)d_ws;
  u16* hb0 = (u16*)ws;                              // 12.8e6
  float* A = (float*)(ws + 25600000);               // 25.6e6 f32 (skip out) / T1 overlay
  u16* mn = (u16*)(ws + 51200000);                  // 12.8e6 bf16 scaled message
  float* agg = (float*)(ws + 64000000);             // 25.6e6 / T2 overlay
  unsigned* deg = (unsigned*)(ws + 89600000);       // 200000
  double* sums3 = (double*)(ws + 89800000);         // 3 x 2048 = 6144
  float* dinv = (float*)(ws + 89806144);            // 200000
  u16* WP = (u16*)(ws + 90006144);                  // 434176 -> ends 90440320
  int* offs = (int*)(ws + 90440320);                // 200000
  int* cursor = (int*)(ws + 90640320);              // 200000
  int* bsum = (int*)(ws + 90840320);                // 1024
  int* boff = (int*)(ws + 90841344);                // 1024
  int* elr = (int*)(ws + 90842368);                 // 3.2e6
  int* ecn = (int*)(ws + 94042368);                 // 3.2e6
  int* eid = (int*)(ws + 97242368);                 // 3.2e6 (end ~100.44 MB)
  u16* T1 = (u16*)A;
  u16* T2 = (u16*)agg;

  u16* WP_ne2 = WP;
  u16* WP_gcn = WP + 16384;
  u16* WP_skip = WP + 65536;
  u16* WP_t4 = WP + 98304;
  u16* WP_ab = WP + 163840;
  u16* WP_ee2 = WP + 180224;
  u16* WP_cl2 = WP + 196608;
  u16* WP_ee1 = WP + 204800;
  u16* WP_eae = WP + 208896;
  u16* WP_ne1 = WP + 212992;

  const int* col = ei + NE;
  const int NGB = (NN + 255) / 256;    // 196 (scan kernels)
  const int NGB128 = (NN + 127) / 128; // 391 (BM=128 GEMMs)

  k_prep<<<848, 256, 0, stream>>>(ea_w1, cl_w1, ee_w2, cl_w2, gcn_w, skip_w, ne_w2, ee_w1, ne_w1, WP);
  hipMemsetAsync(deg, 0, 206144, stream);  // deg (200000) + sums3 (6144), adjacent
  k_deg<<<(NE + 255) / 256, 256, 0, stream>>>(col, deg);
  k_scan1<<<NGB, 256, 0, stream>>>(deg, bsum);
  k_scan2<<<1, 256, 0, stream>>>(bsum, boff, NGB);
  k_scan3<<<NGB, 256, 0, stream>>>(deg, boff, offs, cursor, dinv);
  k_fill<<<(NE + 255) / 256, 256, 0, stream>>>(ei, cursor, elr, ecn, eid);

  k_nodeenc<<<NGB128, 256, 0, stream>>>(x, WP_ne1, WP_ne2, ne_b1, ne_b2, hb0);

  // layer 0: stage bf16 hb0; no skip GEMM
  k_gcnskip<0><<<NGB128, 256, 0, stream>>>(hb0, nullptr, nullptr, nullptr, nullptr,
                                           nullptr, nullptr, WP_gcn, nullptr, dinv, mn, A);
  k_agg<<<(NN + 63) / 64, 256, 0, stream>>>(offs, deg, elr, dinv, mn, gcn_b, agg, sums3);

  // layer 1: stage h1 = relu(BN0(agg)); skip GEMM (Af1 = h1 @ skip_w0)
  k_gcnskip<1><<<NGB128, 256, 0, stream>>>(nullptr, agg, sums3, bn_g, bn_b,
                                           nullptr, nullptr, WP_gcn + 16384, WP_skip, dinv, mn, A);
  k_agg<<<(NN + 63) / 64, 256, 0, stream>>>(offs, deg, elr, dinv, mn, gcn_b + H, agg, sums3 + 256);

  // layer 2: stage h2 = relu(BN1(agg)) + Af1 + skip_b0; skip GEMM (Af2 = h2 @ skip_w1)
  k_gcnskip<2><<<NGB128, 256, 0, stream>>>(nullptr, agg, sums3 + 256, bn_g + H, bn_b + H,
                                           A, skip_b, WP_gcn + 32768, WP_skip + 16384, dinv, mn, A);
  k_agg<<<(NN + 63) / 64, 256, 0, stream>>>(offs, deg, elr, dinv, mn, gcn_b + 2 * H, agg, sums3 + 512);

  // node tables: stage h3 = relu(BN2(agg)) + Af2 + skip_b1; write T1/T2 (overlay A/agg)
  k_ntab<<<NGB128, 256, 0, stream>>>(agg, sums3 + 512, bn_g + 2 * H, bn_b + 2 * H,
                                     A, skip_b + H, WP_t4, ea_b1, cl_b1, T1, T2);

  k_edge<<<NE / EPB, 256, 0, stream>>>(
      elr, ecn, eid, eattr, T1, T2, ee_b1, ee_b2, ea_w2, ea_b2,
      WP_ee1, WP_eae, WP_ee2, WP_ab, WP_cl2, cl_b2, cl_w3, cl_b3, out);
}